// Round 1
// baseline (520.279 us; speedup 1.0000x reference)
//
#include <hip/hip_runtime.h>

#define TT 1024
#define BB 2048
#define K1 8
#define L2E2 2.8853900817779268f  // 2*log2(e)

// DPP helpers ----------------------------------------------------------------
template <int CTRL>
__device__ __forceinline__ float dpp_add(float x) {
  int y = __builtin_amdgcn_update_dpp(0, __float_as_int(x), CTRL, 0xF, 0xF, true);
  return x + __int_as_float(y);
}
// Sum within each aligned 16-lane row; result replicated in all 16 lanes.
__device__ __forceinline__ float sum16(float x) {
  x = dpp_add<0xB1>(x);   // quad_perm xor1
  x = dpp_add<0x4E>(x);   // quad_perm xor2
  x = dpp_add<0x141>(x);  // row_half_mirror
  x = dpp_add<0x140>(x);  // row_mirror
  return x;
}
// Sum within each aligned 32-lane half; replicated in all 32 lanes.
__device__ __forceinline__ float sum32(float x) {
  x = sum16(x);
  int y = __builtin_amdgcn_ds_swizzle(__float_as_int(x), 0x401F);  // lane^16
  return x + __int_as_float(y);
}
__device__ __forceinline__ float rdlane(float x, int l) {
  return __int_as_float(__builtin_amdgcn_readlane(__float_as_int(x), l));
}

// ---------------------------------------------------------------------------
// Fused kernel: sequential RK4 scan + estC output NN. ONE element per wave:
//   row0 = NN1 / state A,  row1 = NN2 / B,  row2 = NN3 / C,  row3 = dummy.
// RK4 per stage: ONE eval stream (2 transcendentals), ONE sum16, P1/P2/P3 via
// v_readlane (lanes 0/16/32), per-lane-coefficient combine.
// estC (12->32->1) fused per step: neuron n = lane&31 (duplicated across wave
// halves), 12 fma on wave-uniform z history (SGPRs) + sigmoid + sum32.
// estC has NO dependence on the RK chain -> fills the ~21% idle issue slots
// measured at VALUBusy=79%, and eliminates the separate ~98us phase-2 kernel.
__global__ __launch_bounds__(256) void phase1_kernel(
    const float* __restrict__ useq, const float* __restrict__ x0,
    const float* __restrict__ r1W0, const float* __restrict__ r1b0,
    const float* __restrict__ r1W1, const float* __restrict__ r1b1,
    const float* __restrict__ r2W0, const float* __restrict__ r2b0,
    const float* __restrict__ r2W1, const float* __restrict__ r2b1,
    const float* __restrict__ r3W0, const float* __restrict__ r3b0,
    const float* __restrict__ r3W1, const float* __restrict__ r3b1,
    const float* __restrict__ eW0, const float* __restrict__ eb0p,
    const float* __restrict__ eW1, const float* __restrict__ eb1p,
    float* __restrict__ out) {
  const int lane = threadIdx.x & 63;
  const int row = lane >> 4;
  const int j = lane & 15;
  // Element id = global wave id; explicitly wave-uniform (SGPR) so that u
  // loads scalarize to s_load.
  const int e =
      __builtin_amdgcn_readfirstlane(blockIdx.x * 4 + (threadIdx.x >> 6));

  const float* W0p = (row == 0) ? r1W0 : (row == 1) ? r2W0 : r3W0;
  const float* b0p = (row == 0) ? r1b0 : (row == 1) ? r2b0 : r3b0;
  const float* W1p = (row == 0) ? r1W1 : (row == 1) ? r2W1 : r3W1;

  const float w0s = W0p[j] * L2E2;
  const float b0s = b0p[j] * L2E2;
  const float wn = -2.0f * W1p[j];

  // C_i = b1_i + sum_j W1_i[j]  (uniform, init-only).
  float C1 = r1b1[0], C2 = r2b1[0], C3 = r3b1[0];
  for (int q = 0; q < 16; ++q) {
    C1 += r1W1[q];
    C2 += r2W1[q];
    C3 += r3W1[q];
  }
  const float caC = 0.2f - C1;
  const float cbC = -1.0f / 6.0f + (5.0f / 3.0f) * C1 - 3.0f * C2 + C3;
  const float ccC = -1.0f / 6.0f + C2 - C3;

  // Per-lane combine coefficients / constants.
  const float cstBase = (row == 0) ? caC : (row == 1) ? cbC : ccC;
  const float uco = (row == 0) ? 0.1f : 0.0f;
  const float a1 = (row == 0) ? -1.0f : (row == 1) ? (5.0f / 3.0f) : 0.0f;
  const float a2 = (row == 1) ? -3.0f : (row == 2) ? 1.0f : 0.0f;
  const float a3 = (row == 1) ? 1.0f : (row == 2) ? -1.0f : 0.0f;

  float S = x0[e * 15 + ((row < 3) ? row : 2)];

  // estC weights: neuron n = lane & 31 (wave halves duplicate; sum32 gives
  // the full 32-neuron sum in every lane).
  const int n = lane & 31;
  float ew0_, ew1_, ew2_, ew3_, ew4_, ew5_, ew6_, ew7_, ew8_, ew9_, ew10_,
      ew11_;
  ew0_ = eW0[0 * 32 + n] * L2E2;
  ew1_ = eW0[1 * 32 + n] * L2E2;
  ew2_ = eW0[2 * 32 + n] * L2E2;
  ew3_ = eW0[3 * 32 + n] * L2E2;
  ew4_ = eW0[4 * 32 + n] * L2E2;
  ew5_ = eW0[5 * 32 + n] * L2E2;
  ew6_ = eW0[6 * 32 + n] * L2E2;
  ew7_ = eW0[7 * 32 + n] * L2E2;
  ew8_ = eW0[8 * 32 + n] * L2E2;
  ew9_ = eW0[9 * 32 + n] * L2E2;
  ew10_ = eW0[10 * 32 + n] * L2E2;
  ew11_ = eW0[11 * 32 + n] * L2E2;
  const float eb0 = eb0p[n] * L2E2;
  const float ew1n = -2.0f * eW1[n];
  float ebase = eb1p[0];
  for (int q = 0; q < 32; ++q) ebase += eW1[q];

  // z-history (wave-uniform scalars): y pairs t-4..t-1, u t-4..t-1.
  const float* zp = x0 + e * 15 + 3;
  float hy0 = zp[0], hy1 = zp[1], hy2 = zp[2], hy3 = zp[3];
  float hy4 = zp[4], hy5 = zp[5], hy6 = zp[6], hy7 = zp[7];
  float hu0 = zp[8], hu1 = zp[9], hu2 = zp[10], hu3 = zp[11];

  const float* up = useq + e * TT;          // SGPR base -> scalar loads
  float* op = out + (size_t)e * TT * 4;

#define STAGE(SS, KK)                                                     \
  {                                                                       \
    float rv = __builtin_amdgcn_rcpf(                                     \
        __builtin_amdgcn_exp2f(fmaf(w0s, (SS), b0s)) + 1.0f);             \
    float q = sum16(wn * rv);                                             \
    float P1 = rdlane(q, 0);                                              \
    float P2 = rdlane(q, 16);                                             \
    float P3 = rdlane(q, 32);                                             \
    float t_ = fmaf(-0.1f, (SS), cstS);                                   \
    t_ = fmaf(a1, P1, t_);                                                \
    t_ = fmaf(a2, P2, t_);                                                \
    KK = fmaf(a3, P3, t_);                                                \
  }

// estC on the CURRENT history (z_t, i.e. before appending y_t/u_t).
#define ESTC(Y3_)                                                         \
  {                                                                       \
    float a_ = eb0;                                                       \
    a_ = fmaf(hy0, ew0_, a_);  a_ = fmaf(hy1, ew1_, a_);                  \
    a_ = fmaf(hy2, ew2_, a_);  a_ = fmaf(hy3, ew3_, a_);                  \
    a_ = fmaf(hy4, ew4_, a_);  a_ = fmaf(hy5, ew5_, a_);                  \
    a_ = fmaf(hy6, ew6_, a_);  a_ = fmaf(hy7, ew7_, a_);                  \
    a_ = fmaf(hu0, ew8_, a_);  a_ = fmaf(hu1, ew9_, a_);                  \
    a_ = fmaf(hu2, ew10_, a_); a_ = fmaf(hu3, ew11_, a_);                 \
    float er_ = __builtin_amdgcn_rcpf(                                    \
        __builtin_amdgcn_exp2f(a_) + 1.0f);                               \
    Y3_ = ebase + sum32(ew1n * er_);                                      \
  }

#define STEP(UQ, SC_)                                                     \
  {                                                                       \
    float y3_;                                                            \
    ESTC(y3_)                                                             \
    const float cstS = fmaf(uco, (UQ), cstBase);                          \
    SC_ = (row == 3) ? y3_ : S;                                           \
    const float yA_ = rdlane(S, 0);                                       \
    const float yB_ = rdlane(S, 16);                                      \
    hy0 = hy2; hy1 = hy3; hy2 = hy4; hy3 = hy5;                           \
    hy4 = hy6; hy5 = hy7; hy6 = yA_; hy7 = yB_;                           \
    hu0 = hu1; hu1 = hu2; hu2 = hu3; hu3 = (UQ);                          \
    float k1, k2, k3, k4;                                                 \
    STAGE(S, k1)                                                          \
    float s2 = fmaf(0.5f, k1, S);                                         \
    STAGE(s2, k2)                                                         \
    float s3 = fmaf(0.5f, k2, S);                                         \
    STAGE(s3, k3)                                                         \
    float s4 = S + k3;                                                    \
    STAGE(s4, k4)                                                         \
    S = fmaf(1.0f / 6.0f, fmaf(2.0f, k2 + k3, k1) + k4, S);               \
  }

  float uc0, uc1, uc2, uc3, uc4, uc5, uc6, uc7;
  {
    float4 a = *(const float4*)(up);
    float4 b = *(const float4*)(up + 4);
    uc0 = a.x; uc1 = a.y; uc2 = a.z; uc3 = a.w;
    uc4 = b.x; uc5 = b.y; uc6 = b.z; uc7 = b.w;
  }

  for (int t0 = 0; t0 < TT; t0 += K1) {
    const int tn = (t0 + K1 <= TT - K1) ? (t0 + K1) : (TT - K1);
    const float4 na = *(const float4*)(up + tn);
    const float4 nb = *(const float4*)(up + tn + 4);

    float sc0, sc1, sc2, sc3, sc4, sc5, sc6, sc7;
    STEP(uc0, sc0)
    STEP(uc1, sc1)
    STEP(uc2, sc2)
    STEP(uc3, sc3)
    STEP(uc4, sc4)
    STEP(uc5, sc5)
    STEP(uc6, sc6)
    STEP(uc7, sc7)

    // Batched stores: lanes 0/16/32/48 write components 0/1/2/3 for 8 steps.
    if (j == 0) {
      float* p = op + t0 * 4 + row;
      p[0] = sc0;  p[4] = sc1;  p[8] = sc2;  p[12] = sc3;
      p[16] = sc4; p[20] = sc5; p[24] = sc6; p[28] = sc7;
    }

    uc0 = na.x; uc1 = na.y; uc2 = na.z; uc3 = na.w;
    uc4 = nb.x; uc5 = nb.y; uc6 = nb.z; uc7 = nb.w;
  }
#undef STEP
#undef ESTC
#undef STAGE
}

// ---------------------------------------------------------------------------
extern "C" void kernel_launch(void* const* d_in, const int* in_sizes, int n_in,
                              void* d_out, int out_size, void* d_ws,
                              size_t ws_size, hipStream_t stream) {
  const float* useq = (const float*)d_in[0];
  const float* x0 = (const float*)d_in[1];
  float* out = (float*)d_out;

  phase1_kernel<<<BB / 4, 256, 0, stream>>>(
      useq, x0,
      (const float*)d_in[2], (const float*)d_in[3], (const float*)d_in[4],
      (const float*)d_in[5], (const float*)d_in[6], (const float*)d_in[7],
      (const float*)d_in[8], (const float*)d_in[9], (const float*)d_in[10],
      (const float*)d_in[11], (const float*)d_in[12], (const float*)d_in[13],
      (const float*)d_in[14], (const float*)d_in[15], (const float*)d_in[16],
      (const float*)d_in[17], out);
}

// Round 2
// 512.359 us; speedup vs baseline: 1.0155x; 1.0155x over previous
//
#include <hip/hip_runtime.h>

#define TT 1024
#define BB 2048
#define K1 8
#define L2E2 2.8853900817779268f  // 2*log2(e)

// DPP helpers ----------------------------------------------------------------
template <int CTRL>
__device__ __forceinline__ float dpp_add(float x) {
  int y = __builtin_amdgcn_update_dpp(0, __float_as_int(x), CTRL, 0xF, 0xF, true);
  return x + __int_as_float(y);
}
// Sum within each aligned 16-lane row; result replicated in all 16 lanes.
__device__ __forceinline__ float sum16(float x) {
  x = dpp_add<0xB1>(x);   // quad_perm xor1
  x = dpp_add<0x4E>(x);   // quad_perm xor2
  x = dpp_add<0x141>(x);  // row_half_mirror
  x = dpp_add<0x140>(x);  // row_mirror
  return x;
}
// Sum of lanes 0..31, valid in lanes 16..31 ONLY. Pure DPP (no LDS pipe, so
// lgkmcnt stays reserved for the wave-uniform s_load u-prefetch; a ds_swizzle
// here forced lgkmcnt(0) drains of the prefetch every step -> +86us in R1).
__device__ __forceinline__ float sum32lo(float x) {
  x = sum16(x);
  x = dpp_add<0x142>(x);  // row_bcast15: lanes16-31 += lane15 (row0 sum)
  return x;
}
__device__ __forceinline__ float rdlane(float x, int l) {
  return __int_as_float(__builtin_amdgcn_readlane(__float_as_int(x), l));
}

// ---------------------------------------------------------------------------
// Fused kernel: sequential RK4 scan + estC output NN. ONE element per wave:
//   row0 = NN1 / state A,  row1 = NN2 / B,  row2 = NN3 / C,  row3 = dummy.
// RK4 per stage: ONE eval stream (2 transcendentals), ONE sum16, P1/P2/P3 via
// v_readlane (lanes 0/16/32), per-lane-coefficient combine.
// estC (12->32->1) fused per step: neuron n = lane&31, 12 fma on wave-uniform
// z history (SGPRs) + sigmoid + DPP-only sum32 (result in lanes 16-31); the
// per-lane fmaf(ew1n, sig, ebase/32) folds the output bias into the sum.
// Comp3 is stored from lane 17 (one cndmask selects y3 there).
__global__ __launch_bounds__(256) void phase1_kernel(
    const float* __restrict__ useq, const float* __restrict__ x0,
    const float* __restrict__ r1W0, const float* __restrict__ r1b0,
    const float* __restrict__ r1W1, const float* __restrict__ r1b1,
    const float* __restrict__ r2W0, const float* __restrict__ r2b0,
    const float* __restrict__ r2W1, const float* __restrict__ r2b1,
    const float* __restrict__ r3W0, const float* __restrict__ r3b0,
    const float* __restrict__ r3W1, const float* __restrict__ r3b1,
    const float* __restrict__ eW0, const float* __restrict__ eb0p,
    const float* __restrict__ eW1, const float* __restrict__ eb1p,
    float* __restrict__ out) {
  const int lane = threadIdx.x & 63;
  const int row = lane >> 4;
  const int j = lane & 15;
  // Element id = global wave id; explicitly wave-uniform (SGPR) so that u
  // loads scalarize to s_load.
  const int e =
      __builtin_amdgcn_readfirstlane(blockIdx.x * 4 + (threadIdx.x >> 6));

  const float* W0p = (row == 0) ? r1W0 : (row == 1) ? r2W0 : r3W0;
  const float* b0p = (row == 0) ? r1b0 : (row == 1) ? r2b0 : r3b0;
  const float* W1p = (row == 0) ? r1W1 : (row == 1) ? r2W1 : r3W1;

  const float w0s = W0p[j] * L2E2;
  const float b0s = b0p[j] * L2E2;
  const float wn = -2.0f * W1p[j];

  // C_i = b1_i + sum_j W1_i[j]  (uniform, init-only).
  float C1 = r1b1[0], C2 = r2b1[0], C3 = r3b1[0];
  for (int q = 0; q < 16; ++q) {
    C1 += r1W1[q];
    C2 += r2W1[q];
    C3 += r3W1[q];
  }
  const float caC = 0.2f - C1;
  const float cbC = -1.0f / 6.0f + (5.0f / 3.0f) * C1 - 3.0f * C2 + C3;
  const float ccC = -1.0f / 6.0f + C2 - C3;

  // Per-lane combine coefficients / constants.
  const float cstBase = (row == 0) ? caC : (row == 1) ? cbC : ccC;
  const float uco = (row == 0) ? 0.1f : 0.0f;
  const float a1 = (row == 0) ? -1.0f : (row == 1) ? (5.0f / 3.0f) : 0.0f;
  const float a2 = (row == 1) ? -3.0f : (row == 2) ? 1.0f : 0.0f;
  const float a3 = (row == 1) ? 1.0f : (row == 2) ? -1.0f : 0.0f;

  float S = x0[e * 15 + ((row < 3) ? row : 2)];

  // estC weights: neuron n = lane & 31 (upper half duplicates, harmless;
  // sum32lo over lanes 0-31 gives the full 32-neuron sum in lanes 16-31).
  const int n = lane & 31;
  const float eb0 = eb0p[n] * L2E2;
  float ew0_ = eW0[0 * 32 + n] * L2E2;
  float ew1_ = eW0[1 * 32 + n] * L2E2;
  float ew2_ = eW0[2 * 32 + n] * L2E2;
  float ew3_ = eW0[3 * 32 + n] * L2E2;
  float ew4_ = eW0[4 * 32 + n] * L2E2;
  float ew5_ = eW0[5 * 32 + n] * L2E2;
  float ew6_ = eW0[6 * 32 + n] * L2E2;
  float ew7_ = eW0[7 * 32 + n] * L2E2;
  float ew8_ = eW0[8 * 32 + n] * L2E2;
  float ew9_ = eW0[9 * 32 + n] * L2E2;
  float ew10_ = eW0[10 * 32 + n] * L2E2;
  float ew11_ = eW0[11 * 32 + n] * L2E2;
  const float ew1n = -2.0f * eW1[n];
  float ebase = eb1p[0];
  for (int q = 0; q < 32; ++q) ebase += eW1[q];
  const float eb32 = ebase * 0.03125f;  // bias folded per-lane into the sum

  // z-history (wave-uniform scalars): y pairs t-4..t-1, u t-4..t-1.
  const float* zp = x0 + e * 15 + 3;
  float hy0 = zp[0], hy1 = zp[1], hy2 = zp[2], hy3 = zp[3];
  float hy4 = zp[4], hy5 = zp[5], hy6 = zp[6], hy7 = zp[7];
  float hu0 = zp[8], hu1 = zp[9], hu2 = zp[10], hu3 = zp[11];

  const float* up = useq + e * TT;          // SGPR base -> scalar loads
  float* op = out + (size_t)e * TT * 4;

  // Store mapping: lanes {0,16,32,17} write comps {0,1,2,3}.
  const bool sflag = (j == 0 && row < 3) || (lane == 17);
  const int soff = (lane == 17) ? 3 : row;

#define STAGE(SS, KK)                                                     \
  {                                                                       \
    float rv = __builtin_amdgcn_rcpf(                                     \
        __builtin_amdgcn_exp2f(fmaf(w0s, (SS), b0s)) + 1.0f);             \
    float q = sum16(wn * rv);                                             \
    float P1 = rdlane(q, 0);                                              \
    float P2 = rdlane(q, 16);                                             \
    float P3 = rdlane(q, 32);                                             \
    float t_ = fmaf(-0.1f, (SS), cstS);                                   \
    t_ = fmaf(a1, P1, t_);                                                \
    t_ = fmaf(a2, P2, t_);                                                \
    KK = fmaf(a3, P3, t_);                                                \
  }

// estC on the CURRENT history (z_t, i.e. before appending y_t/u_t).
// Result valid in lanes 16-31. Pure VALU: 12 fma + exp2+add+rcp + fma + 5 DPP.
#define ESTC(Y3_)                                                         \
  {                                                                       \
    float a_ = fmaf(hy0, ew0_, eb0);                                      \
    a_ = fmaf(hy1, ew1_, a_);                                             \
    a_ = fmaf(hy2, ew2_, a_);  a_ = fmaf(hy3, ew3_, a_);                  \
    a_ = fmaf(hy4, ew4_, a_);  a_ = fmaf(hy5, ew5_, a_);                  \
    a_ = fmaf(hy6, ew6_, a_);  a_ = fmaf(hy7, ew7_, a_);                  \
    a_ = fmaf(hu0, ew8_, a_);  a_ = fmaf(hu1, ew9_, a_);                  \
    a_ = fmaf(hu2, ew10_, a_); a_ = fmaf(hu3, ew11_, a_);                 \
    float er_ = __builtin_amdgcn_rcpf(                                    \
        __builtin_amdgcn_exp2f(a_) + 1.0f);                               \
    Y3_ = sum32lo(fmaf(ew1n, er_, eb32));                                 \
  }

#define STEP(UQ, SC_)                                                     \
  {                                                                       \
    float y3_;                                                            \
    ESTC(y3_)                                                             \
    const float cstS = fmaf(uco, (UQ), cstBase);                          \
    SC_ = (lane == 17) ? y3_ : S;                                         \
    const float yA_ = rdlane(S, 0);                                       \
    const float yB_ = rdlane(S, 16);                                      \
    hy0 = hy2; hy1 = hy3; hy2 = hy4; hy3 = hy5;                           \
    hy4 = hy6; hy5 = hy7; hy6 = yA_; hy7 = yB_;                           \
    hu0 = hu1; hu1 = hu2; hu2 = hu3; hu3 = (UQ);                          \
    float k1, k2, k3, k4;                                                 \
    STAGE(S, k1)                                                          \
    float s2 = fmaf(0.5f, k1, S);                                         \
    STAGE(s2, k2)                                                         \
    float s3 = fmaf(0.5f, k2, S);                                         \
    STAGE(s3, k3)                                                         \
    float s4 = S + k3;                                                    \
    STAGE(s4, k4)                                                         \
    S = fmaf(1.0f / 6.0f, fmaf(2.0f, k2 + k3, k1) + k4, S);               \
  }

  float uc0, uc1, uc2, uc3, uc4, uc5, uc6, uc7;
  {
    float4 a = *(const float4*)(up);
    float4 b = *(const float4*)(up + 4);
    uc0 = a.x; uc1 = a.y; uc2 = a.z; uc3 = a.w;
    uc4 = b.x; uc5 = b.y; uc6 = b.z; uc7 = b.w;
  }

  for (int t0 = 0; t0 < TT; t0 += K1) {
    const int tn = (t0 + K1 <= TT - K1) ? (t0 + K1) : (TT - K1);
    const float4 na = *(const float4*)(up + tn);
    const float4 nb = *(const float4*)(up + tn + 4);

    float sc0, sc1, sc2, sc3, sc4, sc5, sc6, sc7;
    STEP(uc0, sc0)
    STEP(uc1, sc1)
    STEP(uc2, sc2)
    STEP(uc3, sc3)
    STEP(uc4, sc4)
    STEP(uc5, sc5)
    STEP(uc6, sc6)
    STEP(uc7, sc7)

    // Batched stores: lanes 0/16/32/17 write components 0/1/2/3 for 8 steps.
    if (sflag) {
      float* p = op + t0 * 4 + soff;
      p[0] = sc0;  p[4] = sc1;  p[8] = sc2;  p[12] = sc3;
      p[16] = sc4; p[20] = sc5; p[24] = sc6; p[28] = sc7;
    }

    uc0 = na.x; uc1 = na.y; uc2 = na.z; uc3 = na.w;
    uc4 = nb.x; uc5 = nb.y; uc6 = nb.z; uc7 = nb.w;
  }
#undef STEP
#undef ESTC
#undef STAGE
}

// ---------------------------------------------------------------------------
extern "C" void kernel_launch(void* const* d_in, const int* in_sizes, int n_in,
                              void* d_out, int out_size, void* d_ws,
                              size_t ws_size, hipStream_t stream) {
  const float* useq = (const float*)d_in[0];
  const float* x0 = (const float*)d_in[1];
  float* out = (float*)d_out;

  phase1_kernel<<<BB / 4, 256, 0, stream>>>(
      useq, x0,
      (const float*)d_in[2], (const float*)d_in[3], (const float*)d_in[4],
      (const float*)d_in[5], (const float*)d_in[6], (const float*)d_in[7],
      (const float*)d_in[8], (const float*)d_in[9], (const float*)d_in[10],
      (const float*)d_in[11], (const float*)d_in[12], (const float*)d_in[13],
      (const float*)d_in[14], (const float*)d_in[15], (const float*)d_in[16],
      (const float*)d_in[17], out);
}

// Round 3
// 471.904 us; speedup vs baseline: 1.1025x; 1.0857x over previous
//
#include <hip/hip_runtime.h>

#define TT 1024
#define BB 2048
#define K1 8
#define L2E2 2.8853900817779268f  // 2*log2(e)

typedef float v2f __attribute__((ext_vector_type(2)));

// DPP helpers ----------------------------------------------------------------
template <int CTRL>
__device__ __forceinline__ float dpp_add(float x) {
  int y = __builtin_amdgcn_update_dpp(0, __float_as_int(x), CTRL, 0xF, 0xF, true);
  return x + __int_as_float(y);
}
// Sum within each aligned 16-lane row; result replicated in all 16 lanes.
__device__ __forceinline__ float sum16(float x) {
  x = dpp_add<0xB1>(x);   // quad_perm xor1
  x = dpp_add<0x4E>(x);   // quad_perm xor2
  x = dpp_add<0x141>(x);  // row_half_mirror
  x = dpp_add<0x140>(x);  // row_mirror
  return x;
}
__device__ __forceinline__ float rdlane(float x, int l) {
  return __int_as_float(__builtin_amdgcn_readlane(__float_as_int(x), l));
}
// Packed 2xf32 fma (v_pk_fma_f32 on gfx950 when the backend vectorizes).
__device__ __forceinline__ v2f pkfma(float s, v2f w, v2f a) {
  return __builtin_elementwise_fma((v2f){s, s}, w, a);
}

// ---------------------------------------------------------------------------
// Phase 1: sequential RK4 scan. ONE element per 64-lane wave (proven 378us
// version — R1/R2 showed in-wave estC fusion costs +78us vs +41us as a
// separate kernel, so estC stays in phase 2).
__global__ __launch_bounds__(256) void phase1_kernel(
    const float* __restrict__ useq, const float* __restrict__ x0,
    const float* __restrict__ r1W0, const float* __restrict__ r1b0,
    const float* __restrict__ r1W1, const float* __restrict__ r1b1,
    const float* __restrict__ r2W0, const float* __restrict__ r2b0,
    const float* __restrict__ r2W1, const float* __restrict__ r2b1,
    const float* __restrict__ r3W0, const float* __restrict__ r3b0,
    const float* __restrict__ r3W1, const float* __restrict__ r3b1,
    float* __restrict__ out) {
  const int lane = threadIdx.x & 63;
  const int row = lane >> 4;
  const int j = lane & 15;
  const int e =
      __builtin_amdgcn_readfirstlane(blockIdx.x * 4 + (threadIdx.x >> 6));

  const float* W0p = (row == 0) ? r1W0 : (row == 1) ? r2W0 : r3W0;
  const float* b0p = (row == 0) ? r1b0 : (row == 1) ? r2b0 : r3b0;
  const float* W1p = (row == 0) ? r1W1 : (row == 1) ? r2W1 : r3W1;

  const float w0s = W0p[j] * L2E2;
  const float b0s = b0p[j] * L2E2;
  const float wn = -2.0f * W1p[j];

  float C1 = r1b1[0], C2 = r2b1[0], C3 = r3b1[0];
  for (int q = 0; q < 16; ++q) {
    C1 += r1W1[q];
    C2 += r2W1[q];
    C3 += r3W1[q];
  }
  const float caC = 0.2f - C1;
  const float cbC = -1.0f / 6.0f + (5.0f / 3.0f) * C1 - 3.0f * C2 + C3;
  const float ccC = -1.0f / 6.0f + C2 - C3;

  const float cstBase = (row == 0) ? caC : (row == 1) ? cbC : ccC;
  const float uco = (row == 0) ? 0.1f : 0.0f;
  const float a1 = (row == 0) ? -1.0f : (row == 1) ? (5.0f / 3.0f) : 0.0f;
  const float a2 = (row == 1) ? -3.0f : (row == 2) ? 1.0f : 0.0f;
  const float a3 = (row == 1) ? 1.0f : (row == 2) ? -1.0f : 0.0f;

  float S = x0[e * 15 + ((row < 3) ? row : 2)];

  const float* up = useq + e * TT;          // SGPR base -> scalar loads
  float* op = out + (size_t)e * TT * 4;

#define STAGE(SS, KK)                                                     \
  {                                                                       \
    float rv = __builtin_amdgcn_rcpf(                                     \
        __builtin_amdgcn_exp2f(fmaf(w0s, (SS), b0s)) + 1.0f);             \
    float q = sum16(wn * rv);                                             \
    float P1 = rdlane(q, 0);                                              \
    float P2 = rdlane(q, 16);                                             \
    float P3 = rdlane(q, 32);                                             \
    float t_ = fmaf(-0.1f, (SS), cstS);                                   \
    t_ = fmaf(a1, P1, t_);                                                \
    t_ = fmaf(a2, P2, t_);                                                \
    KK = fmaf(a3, P3, t_);                                                \
  }

#define STEP(UQ, SC_)                                                     \
  {                                                                       \
    const float cstS = fmaf(uco, (UQ), cstBase);                          \
    SC_ = S;                                                              \
    float k1, k2, k3, k4;                                                 \
    STAGE(S, k1)                                                          \
    float s2 = fmaf(0.5f, k1, S);                                         \
    STAGE(s2, k2)                                                         \
    float s3 = fmaf(0.5f, k2, S);                                         \
    STAGE(s3, k3)                                                         \
    float s4 = S + k3;                                                    \
    STAGE(s4, k4)                                                         \
    S = fmaf(1.0f / 6.0f, fmaf(2.0f, k2 + k3, k1) + k4, S);               \
  }

  float uc0, uc1, uc2, uc3, uc4, uc5, uc6, uc7;
  {
    float4 a = *(const float4*)(up);
    float4 b = *(const float4*)(up + 4);
    uc0 = a.x; uc1 = a.y; uc2 = a.z; uc3 = a.w;
    uc4 = b.x; uc5 = b.y; uc6 = b.z; uc7 = b.w;
  }

  for (int t0 = 0; t0 < TT; t0 += K1) {
    const int tn = (t0 + K1 <= TT - K1) ? (t0 + K1) : (TT - K1);
    const float4 na = *(const float4*)(up + tn);
    const float4 nb = *(const float4*)(up + tn + 4);

    float sc0, sc1, sc2, sc3, sc4, sc5, sc6, sc7;
    STEP(uc0, sc0)
    STEP(uc1, sc1)
    STEP(uc2, sc2)
    STEP(uc3, sc3)
    STEP(uc4, sc4)
    STEP(uc5, sc5)
    STEP(uc6, sc6)
    STEP(uc7, sc7)

    // Batched stores: lanes 0/16/32 write components 0/1/2 for 8 steps.
    if (j == 0 && row < 3) {
      float* p = op + t0 * 4 + row;
      p[0] = sc0;  p[4] = sc1;  p[8] = sc2;  p[12] = sc3;
      p[16] = sc4; p[20] = sc5; p[24] = sc6; p[28] = sc7;
    }

    uc0 = na.x; uc1 = na.y; uc2 = na.z; uc3 = na.w;
    uc4 = nb.x; uc5 = nb.y; uc6 = nb.z; uc7 = nb.w;
  }
#undef STEP
#undef STAGE
}

// ---------------------------------------------------------------------------
// Phase 2: out[b,t,3] = estC(z_t). One block per batch row; each thread
// handles 4 samples (t = k*256 + tid).
// v2 rewrite: neuron-PAIR evaluation. LDS holds one float4 per (pair, input
// duo): {w[k][2p], w[k][2p+1], w[k+1][2p], w[k+1][2p+1]} -> 12 packed fma
// (v_pk_fma_f32) replace 24 scalar fma per pair; y-history loaded as float2
// (4 dwordx2 instead of 8 dword per sample).
__global__ __launch_bounds__(256) void phase2_kernel(
    const float* __restrict__ useq, const float* __restrict__ x0,
    const float* __restrict__ W0, const float* __restrict__ b0,
    const float* __restrict__ W1, const float* __restrict__ b1p,
    float* __restrict__ out) {
  __shared__ float4 wq[16][8];  // [pair][q]: q=0..5 input duos, q=6 bias/w1n
  for (int idx = threadIdx.x; idx < 128; idx += 256) {
    const int p = idx >> 3, q = idx & 7;
    float4 v = {0.0f, 0.0f, 0.0f, 0.0f};
    if (q < 6) {
      v.x = W0[(2 * q) * 32 + 2 * p] * L2E2;
      v.y = W0[(2 * q) * 32 + 2 * p + 1] * L2E2;
      v.z = W0[(2 * q + 1) * 32 + 2 * p] * L2E2;
      v.w = W0[(2 * q + 1) * 32 + 2 * p + 1] * L2E2;
    } else if (q == 6) {
      v.x = b0[2 * p] * L2E2;
      v.y = b0[2 * p + 1] * L2E2;
      v.z = -2.0f * W1[2 * p];
      v.w = -2.0f * W1[2 * p + 1];
    }
    wq[p][q] = v;
  }
  __syncthreads();

  float base = b1p[0];
#pragma unroll
  for (int h = 0; h < 32; ++h) base += W1[h];  // uniform s_loads, cached

  const int b = blockIdx.x;
  const float* xrow = x0 + b * 15;

  v2f zy[4][4];   // y pairs, ages t-4..t-1
  float zu[4][4]; // u, ages t-4..t-1
#pragma unroll
  for (int k = 0; k < 4; ++k) {
    const int t = k * 256 + (int)threadIdx.x;
    const int g = (b << 10) + t;
    if (t >= 4) {
      const v2f* py = (const v2f*)(out) + (size_t)(g - 4) * 2;
#pragma unroll
      for (int i = 0; i < 4; ++i) zy[k][i] = py[2 * i];  // row i, comps 0,1
      const float* pu = useq + g - 4;
#pragma unroll
      for (int i = 0; i < 4; ++i) zu[k][i] = pu[i];
    } else {  // only k==0, tid<4 diverges here
#pragma unroll
      for (int i = 0; i < 4; ++i) {
        const int s4 = t - 4 + i;
        if (s4 >= 0) {
          const v2f* py = (const v2f*)(out) + (size_t)((b << 10) + s4) * 2;
          zy[k][i] = py[0];
          zu[k][i] = useq[(b << 10) + s4];
        } else {
          zy[k][i] = (v2f){xrow[3 + 2 * (i + t)], xrow[4 + 2 * (i + t)]};
          zu[k][i] = xrow[11 + i + t];
        }
      }
    }
  }

  float ov0 = base, ov1 = base, ov2 = base, ov3 = base;
#pragma unroll
  for (int p = 0; p < 16; ++p) {
    const float4 w01 = wq[p][0];
    const float4 w23 = wq[p][1];
    const float4 w45 = wq[p][2];
    const float4 w67 = wq[p][3];
    const float4 wu01 = wq[p][4];
    const float4 wu23 = wq[p][5];
    const float4 wb = wq[p][6];
#define ACC2(OV, ZY, ZU)                                                  \
  {                                                                       \
    v2f a = (v2f){wb.x, wb.y};                                            \
    a = pkfma(ZY[0].x, (v2f){w01.x, w01.y}, a);                           \
    a = pkfma(ZY[0].y, (v2f){w01.z, w01.w}, a);                           \
    a = pkfma(ZY[1].x, (v2f){w23.x, w23.y}, a);                           \
    a = pkfma(ZY[1].y, (v2f){w23.z, w23.w}, a);                           \
    a = pkfma(ZY[2].x, (v2f){w45.x, w45.y}, a);                           \
    a = pkfma(ZY[2].y, (v2f){w45.z, w45.w}, a);                           \
    a = pkfma(ZY[3].x, (v2f){w67.x, w67.y}, a);                           \
    a = pkfma(ZY[3].y, (v2f){w67.z, w67.w}, a);                           \
    a = pkfma(ZU[0], (v2f){wu01.x, wu01.y}, a);                           \
    a = pkfma(ZU[1], (v2f){wu01.z, wu01.w}, a);                           \
    a = pkfma(ZU[2], (v2f){wu23.x, wu23.y}, a);                           \
    a = pkfma(ZU[3], (v2f){wu23.z, wu23.w}, a);                           \
    const float sx =                                                      \
        __builtin_amdgcn_rcpf(__builtin_amdgcn_exp2f(a.x) + 1.0f);        \
    const float sy =                                                      \
        __builtin_amdgcn_rcpf(__builtin_amdgcn_exp2f(a.y) + 1.0f);        \
    OV = fmaf(wb.z, sx, OV);                                              \
    OV = fmaf(wb.w, sy, OV);                                              \
  }
    ACC2(ov0, zy[0], zu[0])
    ACC2(ov1, zy[1], zu[1])
    ACC2(ov2, zy[2], zu[2])
    ACC2(ov3, zy[3], zu[3])
#undef ACC2
  }

  const size_t gb = (size_t)(b << 10) + threadIdx.x;
  out[(gb + 0) * 4 + 3] = ov0;
  out[(gb + 256) * 4 + 3] = ov1;
  out[(gb + 512) * 4 + 3] = ov2;
  out[(gb + 768) * 4 + 3] = ov3;
}

// ---------------------------------------------------------------------------
extern "C" void kernel_launch(void* const* d_in, const int* in_sizes, int n_in,
                              void* d_out, int out_size, void* d_ws,
                              size_t ws_size, hipStream_t stream) {
  const float* useq = (const float*)d_in[0];
  const float* x0 = (const float*)d_in[1];
  float* out = (float*)d_out;

  phase1_kernel<<<BB / 4, 256, 0, stream>>>(
      useq, x0,
      (const float*)d_in[2], (const float*)d_in[3], (const float*)d_in[4],
      (const float*)d_in[5], (const float*)d_in[6], (const float*)d_in[7],
      (const float*)d_in[8], (const float*)d_in[9], (const float*)d_in[10],
      (const float*)d_in[11], (const float*)d_in[12], (const float*)d_in[13],
      out);

  phase2_kernel<<<BB, 256, 0, stream>>>(
      useq, x0, (const float*)d_in[14], (const float*)d_in[15],
      (const float*)d_in[16], (const float*)d_in[17], out);
}

// Round 4
// 444.978 us; speedup vs baseline: 1.1692x; 1.0605x over previous
//
#include <hip/hip_runtime.h>

#define TT 1024
#define BB 2048
#define K1 8
#define L2E2 2.8853900817779268f  // 2*log2(e)

typedef float v2f __attribute__((ext_vector_type(2)));

// DPP helpers ----------------------------------------------------------------
template <int CTRL>
__device__ __forceinline__ float dpp_add(float x) {
  int y = __builtin_amdgcn_update_dpp(0, __float_as_int(x), CTRL, 0xF, 0xF, true);
  return x + __int_as_float(y);
}
// Sum within each aligned 16-lane row; result replicated in all 16 lanes.
__device__ __forceinline__ float sum16(float x) {
  x = dpp_add<0xB1>(x);   // quad_perm xor1
  x = dpp_add<0x4E>(x);   // quad_perm xor2
  x = dpp_add<0x141>(x);  // row_half_mirror
  x = dpp_add<0x140>(x);  // row_mirror
  return x;
}
__device__ __forceinline__ float rdlane(float x, int l) {
  return __int_as_float(__builtin_amdgcn_readlane(__float_as_int(x), l));
}
// Packed 2xf32 fma (v_pk_fma_f32 on gfx950 when the backend vectorizes).
__device__ __forceinline__ v2f pkfma(float s, v2f w, v2f a) {
  return __builtin_elementwise_fma((v2f){s, s}, w, a);
}

// ---------------------------------------------------------------------------
// Phase 1: sequential RK4 scan. ONE element per 64-lane wave.
// R4 change: fold the post-rcp multiply into the rcp argument:
//   wn*rcp(e+1) == rcp((e+1)*iwn) == rcp(fma(e,iwn,iwn)),  iwn = 1/wn.
// Removes 1 VALU op and 1 dependency level per stage (x4 stages/step).
// (wn==0 edge: iwn=inf -> fma=+/-inf -> rcp=0 == wn*rv. e is always finite.)
__global__ __launch_bounds__(256) void phase1_kernel(
    const float* __restrict__ useq, const float* __restrict__ x0,
    const float* __restrict__ r1W0, const float* __restrict__ r1b0,
    const float* __restrict__ r1W1, const float* __restrict__ r1b1,
    const float* __restrict__ r2W0, const float* __restrict__ r2b0,
    const float* __restrict__ r2W1, const float* __restrict__ r2b1,
    const float* __restrict__ r3W0, const float* __restrict__ r3b0,
    const float* __restrict__ r3W1, const float* __restrict__ r3b1,
    float* __restrict__ out) {
  const int lane = threadIdx.x & 63;
  const int row = lane >> 4;
  const int j = lane & 15;
  const int e =
      __builtin_amdgcn_readfirstlane(blockIdx.x * 4 + (threadIdx.x >> 6));

  const float* W0p = (row == 0) ? r1W0 : (row == 1) ? r2W0 : r3W0;
  const float* b0p = (row == 0) ? r1b0 : (row == 1) ? r2b0 : r3b0;
  const float* W1p = (row == 0) ? r1W1 : (row == 1) ? r2W1 : r3W1;

  const float w0s = W0p[j] * L2E2;
  const float b0s = b0p[j] * L2E2;
  const float wn = -2.0f * W1p[j];
  const float iwn = 1.0f / wn;  // init-only accurate divide

  float C1 = r1b1[0], C2 = r2b1[0], C3 = r3b1[0];
  for (int q = 0; q < 16; ++q) {
    C1 += r1W1[q];
    C2 += r2W1[q];
    C3 += r3W1[q];
  }
  const float caC = 0.2f - C1;
  const float cbC = -1.0f / 6.0f + (5.0f / 3.0f) * C1 - 3.0f * C2 + C3;
  const float ccC = -1.0f / 6.0f + C2 - C3;

  const float cstBase = (row == 0) ? caC : (row == 1) ? cbC : ccC;
  const float uco = (row == 0) ? 0.1f : 0.0f;
  const float a1 = (row == 0) ? -1.0f : (row == 1) ? (5.0f / 3.0f) : 0.0f;
  const float a2 = (row == 1) ? -3.0f : (row == 2) ? 1.0f : 0.0f;
  const float a3 = (row == 1) ? 1.0f : (row == 2) ? -1.0f : 0.0f;

  float S = x0[e * 15 + ((row < 3) ? row : 2)];

  const float* up = useq + e * TT;          // SGPR base -> scalar loads
  float* op = out + (size_t)e * TT * 4;

#define STAGE(SS, KK)                                                     \
  {                                                                       \
    float e_ = __builtin_amdgcn_exp2f(fmaf(w0s, (SS), b0s));              \
    float q = sum16(__builtin_amdgcn_rcpf(fmaf(e_, iwn, iwn)));           \
    float P1 = rdlane(q, 0);                                              \
    float P2 = rdlane(q, 16);                                             \
    float P3 = rdlane(q, 32);                                             \
    float t_ = fmaf(-0.1f, (SS), cstS);                                   \
    t_ = fmaf(a1, P1, t_);                                                \
    t_ = fmaf(a2, P2, t_);                                                \
    KK = fmaf(a3, P3, t_);                                                \
  }

#define STEP(UQ, SC_)                                                     \
  {                                                                       \
    const float cstS = fmaf(uco, (UQ), cstBase);                          \
    SC_ = S;                                                              \
    float k1, k2, k3, k4;                                                 \
    STAGE(S, k1)                                                          \
    float s2 = fmaf(0.5f, k1, S);                                         \
    STAGE(s2, k2)                                                         \
    float s3 = fmaf(0.5f, k2, S);                                         \
    STAGE(s3, k3)                                                         \
    float s4 = S + k3;                                                    \
    STAGE(s4, k4)                                                         \
    S = fmaf(1.0f / 6.0f, fmaf(2.0f, k2 + k3, k1) + k4, S);               \
  }

  float uc0, uc1, uc2, uc3, uc4, uc5, uc6, uc7;
  {
    float4 a = *(const float4*)(up);
    float4 b = *(const float4*)(up + 4);
    uc0 = a.x; uc1 = a.y; uc2 = a.z; uc3 = a.w;
    uc4 = b.x; uc5 = b.y; uc6 = b.z; uc7 = b.w;
  }

  for (int t0 = 0; t0 < TT; t0 += K1) {
    const int tn = (t0 + K1 <= TT - K1) ? (t0 + K1) : (TT - K1);
    const float4 na = *(const float4*)(up + tn);
    const float4 nb = *(const float4*)(up + tn + 4);

    float sc0, sc1, sc2, sc3, sc4, sc5, sc6, sc7;
    STEP(uc0, sc0)
    STEP(uc1, sc1)
    STEP(uc2, sc2)
    STEP(uc3, sc3)
    STEP(uc4, sc4)
    STEP(uc5, sc5)
    STEP(uc6, sc6)
    STEP(uc7, sc7)

    // Batched stores: lanes 0/16/32 write components 0/1/2 for 8 steps.
    if (j == 0 && row < 3) {
      float* p = op + t0 * 4 + row;
      p[0] = sc0;  p[4] = sc1;  p[8] = sc2;  p[12] = sc3;
      p[16] = sc4; p[20] = sc5; p[24] = sc6; p[28] = sc7;
    }

    uc0 = na.x; uc1 = na.y; uc2 = na.z; uc3 = na.w;
    uc4 = nb.x; uc5 = nb.y; uc6 = nb.z; uc7 = nb.w;
  }
#undef STEP
#undef STAGE
}

// ---------------------------------------------------------------------------
// Phase 2: out[b,t,3] = estC(z_t).
// R4 change: 8-sample amortization. One block covers TWO batch rows; each
// thread handles 8 samples (t = k*128 + tid128). The 7 ds_read_b128 per
// neuron-pair are now amortized 8x (halves LDS traffic vs R3), and the
// weight fill runs in half as many blocks (grid 1024).
__global__ __launch_bounds__(256) void phase2_kernel(
    const float* __restrict__ useq, const float* __restrict__ x0,
    const float* __restrict__ W0, const float* __restrict__ b0,
    const float* __restrict__ W1, const float* __restrict__ b1p,
    float* __restrict__ out) {
  __shared__ float4 wq[16][8];  // [pair][q]: q=0..5 input duos, q=6 bias/w1n
  if (threadIdx.x < 128) {
    const int p = threadIdx.x >> 3, q = threadIdx.x & 7;
    float4 v = {0.0f, 0.0f, 0.0f, 0.0f};
    if (q < 6) {
      v.x = W0[(2 * q) * 32 + 2 * p] * L2E2;
      v.y = W0[(2 * q) * 32 + 2 * p + 1] * L2E2;
      v.z = W0[(2 * q + 1) * 32 + 2 * p] * L2E2;
      v.w = W0[(2 * q + 1) * 32 + 2 * p + 1] * L2E2;
    } else if (q == 6) {
      v.x = b0[2 * p] * L2E2;
      v.y = b0[2 * p + 1] * L2E2;
      v.z = -2.0f * W1[2 * p];
      v.w = -2.0f * W1[2 * p + 1];
    }
    wq[p][q] = v;
  }
  __syncthreads();

  float base = b1p[0];
#pragma unroll
  for (int h = 0; h < 32; ++h) base += W1[h];  // uniform s_loads, cached

  const int b = blockIdx.x * 2 + (threadIdx.x >> 7);
  const int tid = threadIdx.x & 127;
  const float* xrow = x0 + b * 15;

  v2f zy[8][4];   // y pairs, ages t-4..t-1
  float zu[8][4]; // u, ages t-4..t-1
#pragma unroll
  for (int k = 0; k < 8; ++k) {
    const int t = k * 128 + tid;
    const int g = (b << 10) + t;
    if (t >= 4) {
      const v2f* py = (const v2f*)(out) + (size_t)(g - 4) * 2;
#pragma unroll
      for (int i = 0; i < 4; ++i) zy[k][i] = py[2 * i];  // row i, comps 0,1
      const float* pu = useq + g - 4;
#pragma unroll
      for (int i = 0; i < 4; ++i) zu[k][i] = pu[i];
    } else {  // only k==0, tid<4 diverges here
#pragma unroll
      for (int i = 0; i < 4; ++i) {
        const int s4 = t - 4 + i;
        if (s4 >= 0) {
          const v2f* py = (const v2f*)(out) + (size_t)((b << 10) + s4) * 2;
          zy[k][i] = py[0];
          zu[k][i] = useq[(b << 10) + s4];
        } else {
          zy[k][i] = (v2f){xrow[3 + 2 * (i + t)], xrow[4 + 2 * (i + t)]};
          zu[k][i] = xrow[11 + i + t];
        }
      }
    }
  }

  float ov0 = base, ov1 = base, ov2 = base, ov3 = base;
  float ov4 = base, ov5 = base, ov6 = base, ov7 = base;
#pragma unroll
  for (int p = 0; p < 16; ++p) {
    const float4 w01 = wq[p][0];
    const float4 w23 = wq[p][1];
    const float4 w45 = wq[p][2];
    const float4 w67 = wq[p][3];
    const float4 wu01 = wq[p][4];
    const float4 wu23 = wq[p][5];
    const float4 wb = wq[p][6];
#define ACC2(OV, ZY, ZU)                                                  \
  {                                                                       \
    v2f a = (v2f){wb.x, wb.y};                                            \
    a = pkfma(ZY[0].x, (v2f){w01.x, w01.y}, a);                           \
    a = pkfma(ZY[0].y, (v2f){w01.z, w01.w}, a);                           \
    a = pkfma(ZY[1].x, (v2f){w23.x, w23.y}, a);                           \
    a = pkfma(ZY[1].y, (v2f){w23.z, w23.w}, a);                           \
    a = pkfma(ZY[2].x, (v2f){w45.x, w45.y}, a);                           \
    a = pkfma(ZY[2].y, (v2f){w45.z, w45.w}, a);                           \
    a = pkfma(ZY[3].x, (v2f){w67.x, w67.y}, a);                           \
    a = pkfma(ZY[3].y, (v2f){w67.z, w67.w}, a);                           \
    a = pkfma(ZU[0], (v2f){wu01.x, wu01.y}, a);                           \
    a = pkfma(ZU[1], (v2f){wu01.z, wu01.w}, a);                           \
    a = pkfma(ZU[2], (v2f){wu23.x, wu23.y}, a);                           \
    a = pkfma(ZU[3], (v2f){wu23.z, wu23.w}, a);                           \
    const float sx =                                                      \
        __builtin_amdgcn_rcpf(__builtin_amdgcn_exp2f(a.x) + 1.0f);        \
    const float sy =                                                      \
        __builtin_amdgcn_rcpf(__builtin_amdgcn_exp2f(a.y) + 1.0f);        \
    OV = fmaf(wb.z, sx, OV);                                              \
    OV = fmaf(wb.w, sy, OV);                                              \
  }
    ACC2(ov0, zy[0], zu[0])
    ACC2(ov1, zy[1], zu[1])
    ACC2(ov2, zy[2], zu[2])
    ACC2(ov3, zy[3], zu[3])
    ACC2(ov4, zy[4], zu[4])
    ACC2(ov5, zy[5], zu[5])
    ACC2(ov6, zy[6], zu[6])
    ACC2(ov7, zy[7], zu[7])
#undef ACC2
  }

  const size_t gb = (size_t)(b << 10) + tid;
  out[(gb + 0) * 4 + 3] = ov0;
  out[(gb + 128) * 4 + 3] = ov1;
  out[(gb + 256) * 4 + 3] = ov2;
  out[(gb + 384) * 4 + 3] = ov3;
  out[(gb + 512) * 4 + 3] = ov4;
  out[(gb + 640) * 4 + 3] = ov5;
  out[(gb + 768) * 4 + 3] = ov6;
  out[(gb + 896) * 4 + 3] = ov7;
}

// ---------------------------------------------------------------------------
extern "C" void kernel_launch(void* const* d_in, const int* in_sizes, int n_in,
                              void* d_out, int out_size, void* d_ws,
                              size_t ws_size, hipStream_t stream) {
  const float* useq = (const float*)d_in[0];
  const float* x0 = (const float*)d_in[1];
  float* out = (float*)d_out;

  phase1_kernel<<<BB / 4, 256, 0, stream>>>(
      useq, x0,
      (const float*)d_in[2], (const float*)d_in[3], (const float*)d_in[4],
      (const float*)d_in[5], (const float*)d_in[6], (const float*)d_in[7],
      (const float*)d_in[8], (const float*)d_in[9], (const float*)d_in[10],
      (const float*)d_in[11], (const float*)d_in[12], (const float*)d_in[13],
      out);

  phase2_kernel<<<BB / 2, 256, 0, stream>>>(
      useq, x0, (const float*)d_in[14], (const float*)d_in[15],
      (const float*)d_in[16], (const float*)d_in[17], out);
}

// Round 5
// 444.280 us; speedup vs baseline: 1.1711x; 1.0016x over previous
//
#include <hip/hip_runtime.h>

#define TT 1024
#define BB 2048
#define L2E2 2.8853900817779268f  // 2*log2(e)

typedef float v2f __attribute__((ext_vector_type(2)));

// DPP helpers ----------------------------------------------------------------
template <int CTRL>
__device__ __forceinline__ float dpp_add(float x) {
  int y = __builtin_amdgcn_update_dpp(0, __float_as_int(x), CTRL, 0xF, 0xF, true);
  return x + __int_as_float(y);
}
__device__ __forceinline__ float rdlane(float x, int l) {
  return __int_as_float(__builtin_amdgcn_readlane(__float_as_int(x), l));
}
// Packed 2xf32 fma (v_pk_fma_f32 on gfx950 when the backend vectorizes).
__device__ __forceinline__ v2f pkfma(float s, v2f w, v2f a) {
  return __builtin_elementwise_fma((v2f){s, s}, w, a);
}

// ---------------------------------------------------------------------------
// Phase 1: sequential RK4 scan. R5 change: TWO elements per 64-lane wave
// (time-interleaved, not lane-split). The two RK chains are independent and
// share all weights/coefficients; interleaving them in one wave provides
// static ILP to fill the ~24% of issue slots where (with 1 chain/wave) both
// resident waves were latency-stalled. Wave count halves: 1024 waves =
// 1 wave/SIMD; per-element instruction count unchanged.
// Fallback: if this regresses (ILP < TLP due to exposed waits), revert to
// R4's one-element kernel.
__global__ __launch_bounds__(256) void phase1_kernel(
    const float* __restrict__ useq, const float* __restrict__ x0,
    const float* __restrict__ r1W0, const float* __restrict__ r1b0,
    const float* __restrict__ r1W1, const float* __restrict__ r1b1,
    const float* __restrict__ r2W0, const float* __restrict__ r2b0,
    const float* __restrict__ r2W1, const float* __restrict__ r2b1,
    const float* __restrict__ r3W0, const float* __restrict__ r3b0,
    const float* __restrict__ r3W1, const float* __restrict__ r3b1,
    float* __restrict__ out) {
  const int lane = threadIdx.x & 63;
  const int row = lane >> 4;
  const int j = lane & 15;
  const int e0 = __builtin_amdgcn_readfirstlane(
      (blockIdx.x * 4 + (threadIdx.x >> 6)) * 2);
  const int e1 = e0 + 1;

  const float* W0p = (row == 0) ? r1W0 : (row == 1) ? r2W0 : r3W0;
  const float* b0p = (row == 0) ? r1b0 : (row == 1) ? r2b0 : r3b0;
  const float* W1p = (row == 0) ? r1W1 : (row == 1) ? r2W1 : r3W1;

  const float w0s = W0p[j] * L2E2;
  const float b0s = b0p[j] * L2E2;
  const float wn = -2.0f * W1p[j];
  const float iwn = 1.0f / wn;  // init-only accurate divide

  float C1 = r1b1[0], C2 = r2b1[0], C3 = r3b1[0];
  for (int q = 0; q < 16; ++q) {
    C1 += r1W1[q];
    C2 += r2W1[q];
    C3 += r3W1[q];
  }
  const float caC = 0.2f - C1;
  const float cbC = -1.0f / 6.0f + (5.0f / 3.0f) * C1 - 3.0f * C2 + C3;
  const float ccC = -1.0f / 6.0f + C2 - C3;

  const float cstBase = (row == 0) ? caC : (row == 1) ? cbC : ccC;
  const float uco = (row == 0) ? 0.1f : 0.0f;
  const float a1 = (row == 0) ? -1.0f : (row == 1) ? (5.0f / 3.0f) : 0.0f;
  const float a2 = (row == 1) ? -3.0f : (row == 2) ? 1.0f : 0.0f;
  const float a3 = (row == 1) ? 1.0f : (row == 2) ? -1.0f : 0.0f;

  const int srow = (row < 3) ? row : 2;
  float S0 = x0[e0 * 15 + srow];
  float S1 = x0[e1 * 15 + srow];

  const float* up0 = useq + e0 * TT;  // SGPR bases -> scalar loads
  const float* up1 = useq + e1 * TT;
  float* op0 = out + (size_t)e0 * TT * 4;
  float* op1 = out + (size_t)e1 * TT * 4;

// One RK stage for BOTH elements, instruction streams interleaved so the
// scheduler can overlap the two independent dependency chains.
#define STAGE2(SA, SB, KA, KB)                                            \
  {                                                                       \
    float ea_ = __builtin_amdgcn_exp2f(fmaf(w0s, (SA), b0s));             \
    float eb_ = __builtin_amdgcn_exp2f(fmaf(w0s, (SB), b0s));             \
    float qa_ = __builtin_amdgcn_rcpf(fmaf(ea_, iwn, iwn));               \
    float qb_ = __builtin_amdgcn_rcpf(fmaf(eb_, iwn, iwn));               \
    qa_ = dpp_add<0xB1>(qa_);   qb_ = dpp_add<0xB1>(qb_);                 \
    qa_ = dpp_add<0x4E>(qa_);   qb_ = dpp_add<0x4E>(qb_);                 \
    qa_ = dpp_add<0x141>(qa_);  qb_ = dpp_add<0x141>(qb_);                \
    qa_ = dpp_add<0x140>(qa_);  qb_ = dpp_add<0x140>(qb_);                \
    float P1a = rdlane(qa_, 0);                                           \
    float P1b = rdlane(qb_, 0);                                           \
    float P2a = rdlane(qa_, 16);                                          \
    float P2b = rdlane(qb_, 16);                                          \
    float P3a = rdlane(qa_, 32);                                          \
    float P3b = rdlane(qb_, 32);                                          \
    float ta_ = fmaf(-0.1f, (SA), cstSa);                                 \
    float tb_ = fmaf(-0.1f, (SB), cstSb);                                 \
    ta_ = fmaf(a1, P1a, ta_);   tb_ = fmaf(a1, P1b, tb_);                 \
    ta_ = fmaf(a2, P2a, ta_);   tb_ = fmaf(a2, P2b, tb_);                 \
    KA = fmaf(a3, P3a, ta_);    KB = fmaf(a3, P3b, tb_);                  \
  }

#define STEP2(UA, UB, SCA, SCB)                                           \
  {                                                                       \
    const float cstSa = fmaf(uco, (UA), cstBase);                         \
    const float cstSb = fmaf(uco, (UB), cstBase);                         \
    SCA = S0;  SCB = S1;                                                  \
    float k1a, k2a, k3a, k4a, k1b, k2b, k3b, k4b;                         \
    STAGE2(S0, S1, k1a, k1b)                                              \
    float s2a = fmaf(0.5f, k1a, S0), s2b = fmaf(0.5f, k1b, S1);           \
    STAGE2(s2a, s2b, k2a, k2b)                                            \
    float s3a = fmaf(0.5f, k2a, S0), s3b = fmaf(0.5f, k2b, S1);           \
    STAGE2(s3a, s3b, k3a, k3b)                                            \
    float s4a = S0 + k3a, s4b = S1 + k3b;                                 \
    STAGE2(s4a, s4b, k4a, k4b)                                            \
    S0 = fmaf(1.0f / 6.0f, fmaf(2.0f, k2a + k3a, k1a) + k4a, S0);         \
    S1 = fmaf(1.0f / 6.0f, fmaf(2.0f, k2b + k3b, k1b) + k4b, S1);         \
  }

  float4 cura = *(const float4*)(up0);
  float4 curb = *(const float4*)(up1);

  for (int t0 = 0; t0 < TT; t0 += 4) {
    const int tn = (t0 + 4 <= TT - 4) ? (t0 + 4) : (TT - 4);
    const float4 naa = *(const float4*)(up0 + tn);
    const float4 nab = *(const float4*)(up1 + tn);

    float sa0, sa1, sa2, sa3, sb0, sb1, sb2, sb3;
    STEP2(cura.x, curb.x, sa0, sb0)
    STEP2(cura.y, curb.y, sa1, sb1)
    STEP2(cura.z, curb.z, sa2, sb2)
    STEP2(cura.w, curb.w, sa3, sb3)

    // Batched stores: lanes 0/16/32 write components 0/1/2 for 4 steps,
    // both elements.
    if (j == 0 && row < 3) {
      float* pa = op0 + t0 * 4 + row;
      pa[0] = sa0;  pa[4] = sa1;  pa[8] = sa2;  pa[12] = sa3;
      float* pb = op1 + t0 * 4 + row;
      pb[0] = sb0;  pb[4] = sb1;  pb[8] = sb2;  pb[12] = sb3;
    }

    cura = naa;
    curb = nab;
  }
#undef STEP2
#undef STAGE2
}

// ---------------------------------------------------------------------------
// Phase 2: out[b,t,3] = estC(z_t).
// R5 change: CONTIGUOUS samples per thread. Thread handles t = 8*tid ..
// 8*tid+7 (128 threads per batch row, 2 rows per block). The 8 samples share
// an 11-row history window: 11 dwordx2 (y-pairs) + 3 dwordx4 (u) = 14 VMEM
// per thread, vs 40 scattered loads in R4; y-bytes fetched halve.
__global__ __launch_bounds__(256) void phase2_kernel(
    const float* __restrict__ useq, const float* __restrict__ x0,
    const float* __restrict__ W0, const float* __restrict__ b0,
    const float* __restrict__ W1, const float* __restrict__ b1p,
    float* __restrict__ out) {
  __shared__ float4 wq[16][8];  // [pair][q]: q=0..5 input duos, q=6 bias/w1n
  if (threadIdx.x < 128) {
    const int p = threadIdx.x >> 3, q = threadIdx.x & 7;
    float4 v = {0.0f, 0.0f, 0.0f, 0.0f};
    if (q < 6) {
      v.x = W0[(2 * q) * 32 + 2 * p] * L2E2;
      v.y = W0[(2 * q) * 32 + 2 * p + 1] * L2E2;
      v.z = W0[(2 * q + 1) * 32 + 2 * p] * L2E2;
      v.w = W0[(2 * q + 1) * 32 + 2 * p + 1] * L2E2;
    } else if (q == 6) {
      v.x = b0[2 * p] * L2E2;
      v.y = b0[2 * p + 1] * L2E2;
      v.z = -2.0f * W1[2 * p];
      v.w = -2.0f * W1[2 * p + 1];
    }
    wq[p][q] = v;
  }
  __syncthreads();

  float base = b1p[0];
#pragma unroll
  for (int h = 0; h < 32; ++h) base += W1[h];  // uniform s_loads, cached

  const int b = blockIdx.x * 2 + (threadIdx.x >> 7);
  const int tid = threadIdx.x & 127;
  const int t0 = tid * 8;
  const float* xrow = x0 + b * 15;

  // History window: hy[i]/hu[i] correspond to time (t0 - 4 + i), i = 0..10.
  // Sample k (t = t0+k) consumes hy[k..k+3], hu[k..k+3].
  v2f hy[11];
  float hu[11];
  if (tid != 0) {
    const float* py = out + ((size_t)(b << 10) + t0 - 4) * 4;
#pragma unroll
    for (int i = 0; i < 11; ++i) hy[i] = *(const v2f*)(py + i * 4);
    const float* pu = useq + (b << 10) + t0 - 4;  // 16B-aligned (8*tid-4)
    const float4 ua = *(const float4*)(pu);
    const float4 ub = *(const float4*)(pu + 4);
    const float4 uc = *(const float4*)(pu + 8);
    hu[0] = ua.x; hu[1] = ua.y; hu[2] = ua.z; hu[3] = ua.w;
    hu[4] = ub.x; hu[5] = ub.y; hu[6] = ub.z; hu[7] = ub.w;
    hu[8] = uc.x; hu[9] = uc.y; hu[10] = uc.z;
  } else {  // t0 == 0: first 4 history entries come from the x0 seed
#pragma unroll
    for (int i = 0; i < 4; ++i) {
      hy[i] = (v2f){xrow[3 + 2 * i], xrow[4 + 2 * i]};
      hu[i] = xrow[11 + i];
    }
    const float* py = out + ((size_t)(b << 10)) * 4;
    const float* pu = useq + (b << 10);
#pragma unroll
    for (int i = 4; i < 11; ++i) {
      hy[i] = *(const v2f*)(py + (i - 4) * 4);
      hu[i] = pu[i - 4];
    }
  }

  float ov[8];
#pragma unroll
  for (int k = 0; k < 8; ++k) ov[k] = base;

#pragma unroll
  for (int p = 0; p < 16; ++p) {
    const float4 w01 = wq[p][0];
    const float4 w23 = wq[p][1];
    const float4 w45 = wq[p][2];
    const float4 w67 = wq[p][3];
    const float4 wu01 = wq[p][4];
    const float4 wu23 = wq[p][5];
    const float4 wb = wq[p][6];
#define ACC2(OV, ZY, ZU)                                                  \
  {                                                                       \
    v2f a = (v2f){wb.x, wb.y};                                            \
    a = pkfma((ZY)[0].x, (v2f){w01.x, w01.y}, a);                         \
    a = pkfma((ZY)[0].y, (v2f){w01.z, w01.w}, a);                         \
    a = pkfma((ZY)[1].x, (v2f){w23.x, w23.y}, a);                         \
    a = pkfma((ZY)[1].y, (v2f){w23.z, w23.w}, a);                         \
    a = pkfma((ZY)[2].x, (v2f){w45.x, w45.y}, a);                         \
    a = pkfma((ZY)[2].y, (v2f){w45.z, w45.w}, a);                         \
    a = pkfma((ZY)[3].x, (v2f){w67.x, w67.y}, a);                         \
    a = pkfma((ZY)[3].y, (v2f){w67.z, w67.w}, a);                         \
    a = pkfma((ZU)[0], (v2f){wu01.x, wu01.y}, a);                         \
    a = pkfma((ZU)[1], (v2f){wu01.z, wu01.w}, a);                         \
    a = pkfma((ZU)[2], (v2f){wu23.x, wu23.y}, a);                         \
    a = pkfma((ZU)[3], (v2f){wu23.z, wu23.w}, a);                         \
    const float sx =                                                      \
        __builtin_amdgcn_rcpf(__builtin_amdgcn_exp2f(a.x) + 1.0f);        \
    const float sy =                                                      \
        __builtin_amdgcn_rcpf(__builtin_amdgcn_exp2f(a.y) + 1.0f);        \
    OV = fmaf(wb.z, sx, OV);                                              \
    OV = fmaf(wb.w, sy, OV);                                              \
  }
#pragma unroll
    for (int k = 0; k < 8; ++k) ACC2(ov[k], (&hy[k]), (&hu[k]))
#undef ACC2
  }

  float* po = out + ((size_t)(b << 10) + t0) * 4 + 3;
#pragma unroll
  for (int k = 0; k < 8; ++k) po[4 * k] = ov[k];
}

// ---------------------------------------------------------------------------
extern "C" void kernel_launch(void* const* d_in, const int* in_sizes, int n_in,
                              void* d_out, int out_size, void* d_ws,
                              size_t ws_size, hipStream_t stream) {
  const float* useq = (const float*)d_in[0];
  const float* x0 = (const float*)d_in[1];
  float* out = (float*)d_out;

  phase1_kernel<<<BB / 8, 256, 0, stream>>>(
      useq, x0,
      (const float*)d_in[2], (const float*)d_in[3], (const float*)d_in[4],
      (const float*)d_in[5], (const float*)d_in[6], (const float*)d_in[7],
      (const float*)d_in[8], (const float*)d_in[9], (const float*)d_in[10],
      (const float*)d_in[11], (const float*)d_in[12], (const float*)d_in[13],
      out);

  phase2_kernel<<<BB / 2, 256, 0, stream>>>(
      useq, x0, (const float*)d_in[14], (const float*)d_in[15],
      (const float*)d_in[16], (const float*)d_in[17], out);
}

// Round 6
// 428.948 us; speedup vs baseline: 1.2129x; 1.0357x over previous
//
#include <hip/hip_runtime.h>

#define TT 1024
#define BB 2048
#define L2E2 2.8853900817779268f  // 2*log2(e)

typedef float v2f __attribute__((ext_vector_type(2)));

// DPP helpers ----------------------------------------------------------------
template <int CTRL>
__device__ __forceinline__ float dpp_add(float x) {
  int y = __builtin_amdgcn_update_dpp(0, __float_as_int(x), CTRL, 0xF, 0xF, true);
  return x + __int_as_float(y);
}
template <int CTRL>
__device__ __forceinline__ float dpp_mov(float x) {
  int y = __builtin_amdgcn_update_dpp(0, __float_as_int(x), CTRL, 0xF, 0xF, true);
  return __int_as_float(y);
}
// Sum within each aligned 8-lane group; result replicated in all 8 lanes.
__device__ __forceinline__ float sum8(float x) {
  x = dpp_add<0xB1>(x);   // quad_perm xor1
  x = dpp_add<0x4E>(x);   // quad_perm xor2
  x = dpp_add<0x141>(x);  // row_half_mirror (xor4 within 8)
  return x;
}
__device__ __forceinline__ float rdlane(float x, int l) {
  return __int_as_float(__builtin_amdgcn_readlane(__float_as_int(x), l));
}
// Packed 2xf32 fma.
__device__ __forceinline__ v2f pkfma(float s, v2f w, v2f a) {
  return __builtin_elementwise_fma((v2f){s, s}, w, a);
}

// ---------------------------------------------------------------------------
// Phase 1: sequential RK4 scan. R6: 8-LANE GROUPS, 2 neurons/lane (v2f pk).
// 2 elements per wave (lanes 0-31 = e0, 32-63 = e1). Groups (8 lanes):
//   g0 = NN2 / state B,  g1 = NN1 / state A,  g2 = NN3 / state C,
//   g3 = NN3 / state C duplicate (keeps ror8 sources finite; never consumed).
// Per stage: pk-fma input, 2x exp2, pk-fma fold, 2x rcp, 1 add, sum8
// (3 DPP hops), combine via own-q + row_ror:8 (B<-P1, g3<-P3) + 4 readlanes
// (B<-P3, C<-P2, per element). Cuts the reduction+extraction stream vs the
// 16-lane layout (~30 -> ~22 instrs/stage for the element pair); the kernel
// is issue-bound (R5: ILP<->TLP swap was duration-neutral), so fewer
// wave-wide instructions is the only lever.
__global__ __launch_bounds__(256) void phase1_kernel(
    const float* __restrict__ useq, const float* __restrict__ x0,
    const float* __restrict__ r1W0, const float* __restrict__ r1b0,
    const float* __restrict__ r1W1, const float* __restrict__ r1b1,
    const float* __restrict__ r2W0, const float* __restrict__ r2b0,
    const float* __restrict__ r2W1, const float* __restrict__ r2b1,
    const float* __restrict__ r3W0, const float* __restrict__ r3b0,
    const float* __restrict__ r3W1, const float* __restrict__ r3b1,
    float* __restrict__ out) {
  const int lane = threadIdx.x & 63;
  const int eh = lane >> 5;         // element half 0/1
  const int g = (lane >> 3) & 3;    // 8-lane group
  const int i = lane & 7;           // neuron lane: neurons i, i+8
  const int e0 = __builtin_amdgcn_readfirstlane(
      (blockIdx.x * 4 + (threadIdx.x >> 6)) * 2);
  const int e = e0 + eh;            // per-lane element

  // NN per group: g0->r2, g1->r1, g2/g3->r3.
  const float* W0p = (g == 1) ? r1W0 : (g == 0) ? r2W0 : r3W0;
  const float* b0p = (g == 1) ? r1b0 : (g == 0) ? r2b0 : r3b0;
  const float* W1p = (g == 1) ? r1W1 : (g == 0) ? r2W1 : r3W1;

  const v2f w0s = {W0p[i] * L2E2, W0p[i + 8] * L2E2};
  const v2f b0s = {b0p[i] * L2E2, b0p[i + 8] * L2E2};
  const v2f iwn = {1.0f / (-2.0f * W1p[i]),
                   1.0f / (-2.0f * W1p[i + 8])};  // init-only divides

  float C1 = r1b1[0], C2 = r2b1[0], C3 = r3b1[0];
  for (int q = 0; q < 16; ++q) {
    C1 += r1W1[q];
    C2 += r2W1[q];
    C3 += r3W1[q];
  }
  const float caC = 0.2f - C1;
  const float cbC = -1.0f / 6.0f + (5.0f / 3.0f) * C1 - 3.0f * C2 + C3;
  const float ccC = -1.0f / 6.0f + C2 - C3;

  // Per-lane state & combine constants.
  const int srow = (g == 1) ? 0 : (g == 0) ? 1 : 2;   // A,B,C
  const float cstBase = (g == 1) ? caC : (g == 0) ? cbC : ccC;
  const float uco = (g == 1) ? 0.1f : 0.0f;
  const float c0 = (g == 0) ? -3.0f : -1.0f;          // own-group P coeff
  const float c1 = (g == 0) ? (5.0f / 3.0f) : 0.0f;   // ror8 (B<-P1)
  const float cR3a = (g == 0 && eh == 0) ? 1.0f : 0.0f;  // B(e0) <- P3(e0)
  const float cR3b = (g == 0 && eh == 1) ? 1.0f : 0.0f;  // B(e1) <- P3(e1)
  const float cR2a = (g >= 2 && eh == 0) ? 1.0f : 0.0f;  // C(e0) <- P2(e0)
  const float cR2b = (g >= 2 && eh == 1) ? 1.0f : 0.0f;  // C(e1) <- P2(e1)

  float S = x0[e * 15 + srow];

  const float* up0 = useq + e0 * TT;        // uniform -> s_load prefetch
  const float* up1 = useq + (e0 + 1) * TT;
  float* op = out + (size_t)e * TT * 4 + srow;  // per-lane store base
  const bool sflag = (i == 0 && g < 3);

#define STAGE(SS, KK)                                                     \
  {                                                                       \
    v2f h = __builtin_elementwise_fma(w0s, (v2f){(SS), (SS)}, b0s);       \
    h.x = __builtin_amdgcn_exp2f(h.x);                                    \
    h.y = __builtin_amdgcn_exp2f(h.y);                                    \
    h = __builtin_elementwise_fma(h, iwn, iwn);                           \
    float rv = __builtin_amdgcn_rcpf(h.x) + __builtin_amdgcn_rcpf(h.y);   \
    float q = sum8(rv);                                                   \
    float sP2a = rdlane(q, 0);                                            \
    float sP3a = rdlane(q, 16);                                           \
    float sP2b = rdlane(q, 32);                                           \
    float sP3b = rdlane(q, 48);                                           \
    float t_ = fmaf(-0.1f, (SS), cstS);                                   \
    t_ = fmaf(c0, q, t_);                                                 \
    t_ = fmaf(c1, dpp_mov<0x128>(q), t_);                                 \
    t_ = fmaf(cR3a, sP3a, t_);                                            \
    t_ = fmaf(cR3b, sP3b, t_);                                            \
    t_ = fmaf(cR2a, sP2a, t_);                                            \
    t_ = fmaf(cR2b, sP2b, t_);                                            \
    KK = t_;                                                              \
  }

#define STEP(UA, UB, SC_)                                                 \
  {                                                                       \
    const float usel = eh ? (UB) : (UA);                                  \
    const float cstS = fmaf(uco, usel, cstBase);                          \
    SC_ = S;                                                              \
    float k1, k2, k3, k4;                                                 \
    STAGE(S, k1)                                                          \
    float s2 = fmaf(0.5f, k1, S);                                         \
    STAGE(s2, k2)                                                         \
    float s3 = fmaf(0.5f, k2, S);                                         \
    STAGE(s3, k3)                                                         \
    float s4 = S + k3;                                                    \
    STAGE(s4, k4)                                                         \
    S = fmaf(1.0f / 6.0f, fmaf(2.0f, k2 + k3, k1) + k4, S);               \
  }

  float4 cura = *(const float4*)(up0);
  float4 curb = *(const float4*)(up1);

  for (int t0 = 0; t0 < TT; t0 += 4) {
    const int tn = (t0 + 4 <= TT - 4) ? (t0 + 4) : (TT - 4);
    const float4 naa = *(const float4*)(up0 + tn);
    const float4 nab = *(const float4*)(up1 + tn);

    float sc0, sc1, sc2, sc3;
    STEP(cura.x, curb.x, sc0)
    STEP(cura.y, curb.y, sc1)
    STEP(cura.z, curb.z, sc2)
    STEP(cura.w, curb.w, sc3)

    // Batched stores: lanes {8,0,16}(e0) / {40,32,48}(e1) write comps
    // {0,1,2} for 4 steps.
    if (sflag) {
      float* p = op + t0 * 4;
      p[0] = sc0;  p[4] = sc1;  p[8] = sc2;  p[12] = sc3;
    }

    cura = naa;
    curb = nab;
  }
#undef STEP
#undef STAGE
}

// ---------------------------------------------------------------------------
// Phase 2: out[b,t,3] = estC(z_t). (Unchanged from R5.)
__global__ __launch_bounds__(256) void phase2_kernel(
    const float* __restrict__ useq, const float* __restrict__ x0,
    const float* __restrict__ W0, const float* __restrict__ b0,
    const float* __restrict__ W1, const float* __restrict__ b1p,
    float* __restrict__ out) {
  __shared__ float4 wq[16][8];  // [pair][q]: q=0..5 input duos, q=6 bias/w1n
  if (threadIdx.x < 128) {
    const int p = threadIdx.x >> 3, q = threadIdx.x & 7;
    float4 v = {0.0f, 0.0f, 0.0f, 0.0f};
    if (q < 6) {
      v.x = W0[(2 * q) * 32 + 2 * p] * L2E2;
      v.y = W0[(2 * q) * 32 + 2 * p + 1] * L2E2;
      v.z = W0[(2 * q + 1) * 32 + 2 * p] * L2E2;
      v.w = W0[(2 * q + 1) * 32 + 2 * p + 1] * L2E2;
    } else if (q == 6) {
      v.x = b0[2 * p] * L2E2;
      v.y = b0[2 * p + 1] * L2E2;
      v.z = -2.0f * W1[2 * p];
      v.w = -2.0f * W1[2 * p + 1];
    }
    wq[p][q] = v;
  }
  __syncthreads();

  float base = b1p[0];
#pragma unroll
  for (int h = 0; h < 32; ++h) base += W1[h];  // uniform s_loads, cached

  const int b = blockIdx.x * 2 + (threadIdx.x >> 7);
  const int tid = threadIdx.x & 127;
  const int t0 = tid * 8;
  const float* xrow = x0 + b * 15;

  // History window: hy[i]/hu[i] correspond to time (t0 - 4 + i), i = 0..10.
  v2f hy[11];
  float hu[11];
  if (tid != 0) {
    const float* py = out + ((size_t)(b << 10) + t0 - 4) * 4;
#pragma unroll
    for (int i = 0; i < 11; ++i) hy[i] = *(const v2f*)(py + i * 4);
    const float* pu = useq + (b << 10) + t0 - 4;  // 16B-aligned (8*tid-4)
    const float4 ua = *(const float4*)(pu);
    const float4 ub = *(const float4*)(pu + 4);
    const float4 uc = *(const float4*)(pu + 8);
    hu[0] = ua.x; hu[1] = ua.y; hu[2] = ua.z; hu[3] = ua.w;
    hu[4] = ub.x; hu[5] = ub.y; hu[6] = ub.z; hu[7] = ub.w;
    hu[8] = uc.x; hu[9] = uc.y; hu[10] = uc.z;
  } else {  // t0 == 0: first 4 history entries come from the x0 seed
#pragma unroll
    for (int i = 0; i < 4; ++i) {
      hy[i] = (v2f){xrow[3 + 2 * i], xrow[4 + 2 * i]};
      hu[i] = xrow[11 + i];
    }
    const float* py = out + ((size_t)(b << 10)) * 4;
    const float* pu = useq + (b << 10);
#pragma unroll
    for (int i = 4; i < 11; ++i) {
      hy[i] = *(const v2f*)(py + (i - 4) * 4);
      hu[i] = pu[i - 4];
    }
  }

  float ov[8];
#pragma unroll
  for (int k = 0; k < 8; ++k) ov[k] = base;

#pragma unroll
  for (int p = 0; p < 16; ++p) {
    const float4 w01 = wq[p][0];
    const float4 w23 = wq[p][1];
    const float4 w45 = wq[p][2];
    const float4 w67 = wq[p][3];
    const float4 wu01 = wq[p][4];
    const float4 wu23 = wq[p][5];
    const float4 wb = wq[p][6];
#define ACC2(OV, ZY, ZU)                                                  \
  {                                                                       \
    v2f a = (v2f){wb.x, wb.y};                                            \
    a = pkfma((ZY)[0].x, (v2f){w01.x, w01.y}, a);                         \
    a = pkfma((ZY)[0].y, (v2f){w01.z, w01.w}, a);                         \
    a = pkfma((ZY)[1].x, (v2f){w23.x, w23.y}, a);                         \
    a = pkfma((ZY)[1].y, (v2f){w23.z, w23.w}, a);                         \
    a = pkfma((ZY)[2].x, (v2f){w45.x, w45.y}, a);                         \
    a = pkfma((ZY)[2].y, (v2f){w45.z, w45.w}, a);                         \
    a = pkfma((ZY)[3].x, (v2f){w67.x, w67.y}, a);                         \
    a = pkfma((ZY)[3].y, (v2f){w67.z, w67.w}, a);                         \
    a = pkfma((ZU)[0], (v2f){wu01.x, wu01.y}, a);                         \
    a = pkfma((ZU)[1], (v2f){wu01.z, wu01.w}, a);                         \
    a = pkfma((ZU)[2], (v2f){wu23.x, wu23.y}, a);                         \
    a = pkfma((ZU)[3], (v2f){wu23.z, wu23.w}, a);                         \
    const float sx =                                                      \
        __builtin_amdgcn_rcpf(__builtin_amdgcn_exp2f(a.x) + 1.0f);        \
    const float sy =                                                      \
        __builtin_amdgcn_rcpf(__builtin_amdgcn_exp2f(a.y) + 1.0f);        \
    OV = fmaf(wb.z, sx, OV);                                              \
    OV = fmaf(wb.w, sy, OV);                                              \
  }
#pragma unroll
    for (int k = 0; k < 8; ++k) ACC2(ov[k], (&hy[k]), (&hu[k]))
#undef ACC2
  }

  float* po = out + ((size_t)(b << 10) + t0) * 4 + 3;
#pragma unroll
  for (int k = 0; k < 8; ++k) po[4 * k] = ov[k];
}

// ---------------------------------------------------------------------------
extern "C" void kernel_launch(void* const* d_in, const int* in_sizes, int n_in,
                              void* d_out, int out_size, void* d_ws,
                              size_t ws_size, hipStream_t stream) {
  const float* useq = (const float*)d_in[0];
  const float* x0 = (const float*)d_in[1];
  float* out = (float*)d_out;

  phase1_kernel<<<BB / 8, 256, 0, stream>>>(
      useq, x0,
      (const float*)d_in[2], (const float*)d_in[3], (const float*)d_in[4],
      (const float*)d_in[5], (const float*)d_in[6], (const float*)d_in[7],
      (const float*)d_in[8], (const float*)d_in[9], (const float*)d_in[10],
      (const float*)d_in[11], (const float*)d_in[12], (const float*)d_in[13],
      out);

  phase2_kernel<<<BB / 2, 256, 0, stream>>>(
      useq, x0, (const float*)d_in[14], (const float*)d_in[15],
      (const float*)d_in[16], (const float*)d_in[17], out);
}

// Round 7
// 426.932 us; speedup vs baseline: 1.2186x; 1.0047x over previous
//
#include <hip/hip_runtime.h>

#define TT 1024
#define BB 2048
#define L2E2 2.8853900817779268f  // 2*log2(e)

typedef float v2f __attribute__((ext_vector_type(2)));

// DPP helpers ----------------------------------------------------------------
template <int CTRL>
__device__ __forceinline__ float dpp_add(float x) {
  int y = __builtin_amdgcn_update_dpp(0, __float_as_int(x), CTRL, 0xF, 0xF, true);
  return x + __int_as_float(y);
}
template <int CTRL>
__device__ __forceinline__ float dpp_mov(float x) {
  int y = __builtin_amdgcn_update_dpp(0, __float_as_int(x), CTRL, 0xF, 0xF, true);
  return __int_as_float(y);
}
// Sum within each aligned 8-lane group; result replicated in all 8 lanes.
__device__ __forceinline__ float sum8(float x) {
  x = dpp_add<0xB1>(x);   // quad_perm xor1
  x = dpp_add<0x4E>(x);   // quad_perm xor2
  x = dpp_add<0x141>(x);  // row_half_mirror (xor4 within 8)
  return x;
}
__device__ __forceinline__ float rdlane(float x, int l) {
  return __int_as_float(__builtin_amdgcn_readlane(__float_as_int(x), l));
}

// ---------------------------------------------------------------------------
// Fully fused kernel: RK4 scan + estC. R7: R6's lean 8-lane-group RK core is
// latency-bound at 1 wave/SIMD (VALUBusy 59%, 325 stall-cy/step). estC
// (12->32->1) is dependency-independent of the RK chain (~31 wave-instrs,
// 2 trans per step for BOTH elements) and slots into those bubbles; phase 2
// (~33us + its HBM re-reads) is deleted. [R1's fusion failed in the 2-wave
// 79%-busy regime; this is a different regime bet.]
//
// Wave layout (2 elements: e0 = lanes 0-31, e1 = 32-63). Per half:
//   g0 = NN2/B (lanes 0-7), g1 = NN1/A (8-15), g2 = NN3/C (16-23),
//   g3 = NN3/C dup (24-31) -> stores comp3 (estC), keeps ror8 finite.
// estC: 1 neuron/lane (n = lane&31), sum16 + row_bcast15 => full 32-neuron
// sums valid in rows 1 and 3 (covers g3 store lanes 24-31 / 56-63).
// History (z) in registers, 4-step unroll renaming (12 movs / 4 steps).
__global__ __launch_bounds__(256) void phase1_kernel(
    const float* __restrict__ useq, const float* __restrict__ x0,
    const float* __restrict__ r1W0, const float* __restrict__ r1b0,
    const float* __restrict__ r1W1, const float* __restrict__ r1b1,
    const float* __restrict__ r2W0, const float* __restrict__ r2b0,
    const float* __restrict__ r2W1, const float* __restrict__ r2b1,
    const float* __restrict__ r3W0, const float* __restrict__ r3b0,
    const float* __restrict__ r3W1, const float* __restrict__ r3b1,
    const float* __restrict__ eW0, const float* __restrict__ eb0p,
    const float* __restrict__ eW1, const float* __restrict__ eb1p,
    float* __restrict__ out) {
  const int lane = threadIdx.x & 63;
  const int eh = lane >> 5;         // element half 0/1
  const int g = (lane >> 3) & 3;    // 8-lane group
  const int i = lane & 7;           // neuron lane within RK group
  const int e0 = __builtin_amdgcn_readfirstlane(
      (blockIdx.x * 4 + (threadIdx.x >> 6)) * 2);
  const int e = e0 + eh;            // per-lane element

  // RK NN per group: g0->r2, g1->r1, g2/g3->r3.
  const float* W0p = (g == 1) ? r1W0 : (g == 0) ? r2W0 : r3W0;
  const float* b0p = (g == 1) ? r1b0 : (g == 0) ? r2b0 : r3b0;
  const float* W1p = (g == 1) ? r1W1 : (g == 0) ? r2W1 : r3W1;

  const v2f w0s = {W0p[i] * L2E2, W0p[i + 8] * L2E2};
  const v2f b0s = {b0p[i] * L2E2, b0p[i + 8] * L2E2};
  const v2f iwn = {1.0f / (-2.0f * W1p[i]),
                   1.0f / (-2.0f * W1p[i + 8])};  // init-only divides

  float C1 = r1b1[0], C2 = r2b1[0], C3 = r3b1[0];
  for (int q = 0; q < 16; ++q) {
    C1 += r1W1[q];
    C2 += r2W1[q];
    C3 += r3W1[q];
  }
  const float caC = 0.2f - C1;
  const float cbC = -1.0f / 6.0f + (5.0f / 3.0f) * C1 - 3.0f * C2 + C3;
  const float ccC = -1.0f / 6.0f + C2 - C3;

  // Per-lane RK state & combine constants.
  const int strow = (g == 1) ? 0 : (g == 0) ? 1 : 2;  // state row (g3 = C)
  const float cstBase = (g == 1) ? caC : (g == 0) ? cbC : ccC;
  const float uco = (g == 1) ? 0.1f : 0.0f;
  const float c0 = (g == 0) ? -3.0f : -1.0f;          // own-group P coeff
  const float c1 = (g == 0) ? (5.0f / 3.0f) : 0.0f;   // ror8 (B<-P1)
  const float cR3a = (g == 0 && eh == 0) ? 1.0f : 0.0f;  // B(e0) <- P3(e0)
  const float cR3b = (g == 0 && eh == 1) ? 1.0f : 0.0f;  // B(e1) <- P3(e1)
  const float cR2a = (g >= 2 && eh == 0) ? 1.0f : 0.0f;  // C(e0) <- P2(e0)
  const float cR2b = (g >= 2 && eh == 1) ? 1.0f : 0.0f;  // C(e1) <- P2(e1)

  float S = x0[e * 15 + strow];

  // estC weights: neuron n = lane & 31.
  const int n = lane & 31;
  const float eb0v = eb0p[n] * L2E2;
  const float ew0 = eW0[0 * 32 + n] * L2E2;
  const float ew1 = eW0[1 * 32 + n] * L2E2;
  const float ew2 = eW0[2 * 32 + n] * L2E2;
  const float ew3 = eW0[3 * 32 + n] * L2E2;
  const float ew4 = eW0[4 * 32 + n] * L2E2;
  const float ew5 = eW0[5 * 32 + n] * L2E2;
  const float ew6 = eW0[6 * 32 + n] * L2E2;
  const float ew7 = eW0[7 * 32 + n] * L2E2;
  const float ew8 = eW0[8 * 32 + n] * L2E2;
  const float ew9 = eW0[9 * 32 + n] * L2E2;
  const float ew10 = eW0[10 * 32 + n] * L2E2;
  const float ew11 = eW0[11 * 32 + n] * L2E2;
  const float ew1n = -2.0f * eW1[n];
  float ebs = eb1p[0];
  for (int q = 0; q < 32; ++q) ebs += eW1[q];
  const float eb32 = ebs * 0.03125f;  // output bias folded per-lane

  // z-history (per-lane regs, own element's): pairs (A,B) oldest..newest.
  const float* zp = x0 + e * 15 + 3;
  float hA0 = zp[0], hB0 = zp[1], hA1 = zp[2], hB1 = zp[3];
  float hA2 = zp[4], hB2 = zp[5], hA3 = zp[6], hB3 = zp[7];
  float hU0 = zp[8], hU1 = zp[9], hU2 = zp[10], hU3 = zp[11];

  const float* up0 = useq + e0 * TT;        // uniform -> s_load prefetch
  const float* up1 = useq + (e0 + 1) * TT;
  const int soff = (g == 1) ? 0 : (g == 0) ? 1 : (g == 2) ? 2 : 3;
  float* op = out + (size_t)e * TT * 4 + soff;
  const bool sflag = (i == 0);
  const bool isg3 = (g == 3);

#define STAGE(SS, KK)                                                     \
  {                                                                       \
    v2f h = __builtin_elementwise_fma(w0s, (v2f){(SS), (SS)}, b0s);       \
    h.x = __builtin_amdgcn_exp2f(h.x);                                    \
    h.y = __builtin_amdgcn_exp2f(h.y);                                    \
    h = __builtin_elementwise_fma(h, iwn, iwn);                           \
    float rv = __builtin_amdgcn_rcpf(h.x) + __builtin_amdgcn_rcpf(h.y);   \
    float q = sum8(rv);                                                   \
    float sP2a = rdlane(q, 0);                                            \
    float sP3a = rdlane(q, 16);                                           \
    float sP2b = rdlane(q, 32);                                           \
    float sP3b = rdlane(q, 48);                                           \
    float t_ = fmaf(-0.1f, (SS), cstS);                                   \
    t_ = fmaf(c0, q, t_);                                                 \
    t_ = fmaf(c1, dpp_mov<0x128>(q), t_);                                 \
    t_ = fmaf(cR3a, sP3a, t_);                                            \
    t_ = fmaf(cR3b, sP3b, t_);                                            \
    t_ = fmaf(cR2a, sP2a, t_);                                            \
    t_ = fmaf(cR2b, sP2b, t_);                                            \
    KK = t_;                                                              \
  }

// One time-step for both elements. estC first (independent chain -> fills
// RK stalls); history passed/produced by name (zero-cost rotation).
#define STEP(UA, UB, SC_, hA0_, hB0_, hA1_, hB1_, hA2_, hB2_, hA3_, hB3_, \
             hU0_, hU1_, hU2_, hU3_, NA_, NB_, NU_)                       \
  {                                                                       \
    float a_ = fmaf((hA0_), ew0, eb0v);                                   \
    a_ = fmaf((hB0_), ew1, a_);                                           \
    a_ = fmaf((hA1_), ew2, a_);                                           \
    a_ = fmaf((hB1_), ew3, a_);                                           \
    a_ = fmaf((hA2_), ew4, a_);                                           \
    a_ = fmaf((hB2_), ew5, a_);                                           \
    a_ = fmaf((hA3_), ew6, a_);                                           \
    a_ = fmaf((hB3_), ew7, a_);                                           \
    a_ = fmaf((hU0_), ew8, a_);                                           \
    a_ = fmaf((hU1_), ew9, a_);                                           \
    a_ = fmaf((hU2_), ew10, a_);                                          \
    a_ = fmaf((hU3_), ew11, a_);                                          \
    float er_ = __builtin_amdgcn_rcpf(__builtin_amdgcn_exp2f(a_) + 1.0f); \
    float ps_ = fmaf(ew1n, er_, eb32);                                    \
    ps_ = dpp_add<0xB1>(ps_);                                             \
    ps_ = dpp_add<0x4E>(ps_);                                             \
    ps_ = dpp_add<0x141>(ps_);                                            \
    ps_ = dpp_add<0x140>(ps_);   /* per-16-row sums */                    \
    ps_ = dpp_add<0x142>(ps_);   /* rows 1,3: full 32-neuron sums */      \
    const float sBa_ = rdlane(S, 0);                                      \
    const float sAa_ = rdlane(S, 8);                                      \
    const float sBb_ = rdlane(S, 32);                                     \
    const float sAb_ = rdlane(S, 40);                                     \
    NA_ = eh ? sAb_ : sAa_;                                               \
    NB_ = eh ? sBb_ : sBa_;                                               \
    const float usel_ = eh ? (UB) : (UA);                                 \
    NU_ = usel_;                                                          \
    const float cstS = fmaf(uco, usel_, cstBase);                         \
    SC_ = isg3 ? ps_ : S;                                                 \
    float k1, k2, k3, k4;                                                 \
    STAGE(S, k1)                                                          \
    float s2 = fmaf(0.5f, k1, S);                                         \
    STAGE(s2, k2)                                                         \
    float s3 = fmaf(0.5f, k2, S);                                         \
    STAGE(s3, k3)                                                         \
    float s4 = S + k3;                                                    \
    STAGE(s4, k4)                                                         \
    S = fmaf(1.0f / 6.0f, fmaf(2.0f, k2 + k3, k1) + k4, S);               \
  }

  float4 cura = *(const float4*)(up0);
  float4 curb = *(const float4*)(up1);

  for (int t0 = 0; t0 < TT; t0 += 4) {
    const int tn = (t0 + 4 <= TT - 4) ? (t0 + 4) : (TT - 4);
    const float4 naa = *(const float4*)(up0 + tn);
    const float4 nab = *(const float4*)(up1 + tn);

    float sc0, sc1, sc2, sc3;
    float A4, B4, U4, A5, B5, U5, A6, B6, U6, A7, B7, U7;
    STEP(cura.x, curb.x, sc0, hA0, hB0, hA1, hB1, hA2, hB2, hA3, hB3,
         hU0, hU1, hU2, hU3, A4, B4, U4)
    STEP(cura.y, curb.y, sc1, hA1, hB1, hA2, hB2, hA3, hB3, A4, B4,
         hU1, hU2, hU3, U4, A5, B5, U5)
    STEP(cura.z, curb.z, sc2, hA2, hB2, hA3, hB3, A4, B4, A5, B5,
         hU2, hU3, U4, U5, A6, B6, U6)
    STEP(cura.w, curb.w, sc3, hA3, hB3, A4, B4, A5, B5, A6, B6,
         hU3, U4, U5, U6, A7, B7, U7)

    // Batched stores: lanes 0/8/16/24 (e0) and 32/40/48/56 (e1) write
    // comps 1/0/2/3 for 4 steps.
    if (sflag) {
      float* p = op + t0 * 4;
      p[0] = sc0;  p[4] = sc1;  p[8] = sc2;  p[12] = sc3;
    }

    hA0 = A4; hB0 = B4; hA1 = A5; hB1 = B5;
    hA2 = A6; hB2 = B6; hA3 = A7; hB3 = B7;
    hU0 = U4; hU1 = U5; hU2 = U6; hU3 = U7;

    cura = naa;
    curb = nab;
  }
#undef STEP
#undef STAGE
}

// ---------------------------------------------------------------------------
extern "C" void kernel_launch(void* const* d_in, const int* in_sizes, int n_in,
                              void* d_out, int out_size, void* d_ws,
                              size_t ws_size, hipStream_t stream) {
  const float* useq = (const float*)d_in[0];
  const float* x0 = (const float*)d_in[1];
  float* out = (float*)d_out;

  phase1_kernel<<<BB / 8, 256, 0, stream>>>(
      useq, x0,
      (const float*)d_in[2], (const float*)d_in[3], (const float*)d_in[4],
      (const float*)d_in[5], (const float*)d_in[6], (const float*)d_in[7],
      (const float*)d_in[8], (const float*)d_in[9], (const float*)d_in[10],
      (const float*)d_in[11], (const float*)d_in[12], (const float*)d_in[13],
      (const float*)d_in[14], (const float*)d_in[15], (const float*)d_in[16],
      (const float*)d_in[17], out);
}

// Round 8
// 387.977 us; speedup vs baseline: 1.3410x; 1.1004x over previous
//
#include <hip/hip_runtime.h>

#define TT 1024
#define BB 2048
#define L2E2 2.8853900817779268f  // 2*log2(e)

typedef float v2f __attribute__((ext_vector_type(2)));

// DPP helpers ----------------------------------------------------------------
template <int CTRL>
__device__ __forceinline__ float dpp_add(float x) {
  int y = __builtin_amdgcn_update_dpp(0, __float_as_int(x), CTRL, 0xF, 0xF, true);
  return x + __int_as_float(y);
}
template <int CTRL>
__device__ __forceinline__ float dpp_mov(float x) {
  int y = __builtin_amdgcn_update_dpp(0, __float_as_int(x), CTRL, 0xF, 0xF, true);
  return __int_as_float(y);
}
// Sum within each aligned 8-lane group; result replicated in all 8 lanes.
__device__ __forceinline__ float sum8(float x) {
  x = dpp_add<0xB1>(x);   // quad_perm xor1
  x = dpp_add<0x4E>(x);   // quad_perm xor2
  x = dpp_add<0x141>(x);  // row_half_mirror (xor4 within 8)
  return x;
}
__device__ __forceinline__ float rdlane(float x, int l) {
  return __int_as_float(__builtin_amdgcn_readlane(__float_as_int(x), l));
}

// ---------------------------------------------------------------------------
// Fused RK4 scan + estC. R8: COMMUNICATION-FREE stage layout.
// Per 32-half (e0 = lanes 0-31, e1 = 32-63):
//   row0: g0 = NN1/A (0-7),  g1 = NN1dup/Ad (8-15)  [exact mirror of A]
//   row1: g2 = NN3/C (16-23), g3 = NN2/B (24-31)
// Cross-lane P delivery per stage (NO readlane, 2 DPP movs):
//   qr = row_ror:8(q): C-lanes <- P2 (B's q), B-lanes <- P3 (C's q)
//   m2 = row_bcast15(qr): row1 <- qr[15] = q[7] = P1  (per-half correct:
//        lanes 48-63 <- qr[47] = q[39] = P1(e1); contaminated lanes have
//        coefficient 0; lanes 0-15 read 0 via bound_ctrl)
// Combine: t = fma(-0.1,S,cstS); + c_own*q + c_qr*qr + c_m2*m2.
//   A/Ad: own P1 (-1).  C: own P3 (-1), qr P2 (+1).
//   B: own P2 (-3), qr P3 (+1), m2 P1 (+5/3).
// Stage = 16 wave-instrs (was 22). estC unchanged from R7 except comp3
// stores from lane 17/49 (estC 32-sums land in rows 1,3 via sum16+bcast15).
__global__ __launch_bounds__(256) void phase1_kernel(
    const float* __restrict__ useq, const float* __restrict__ x0,
    const float* __restrict__ r1W0, const float* __restrict__ r1b0,
    const float* __restrict__ r1W1, const float* __restrict__ r1b1,
    const float* __restrict__ r2W0, const float* __restrict__ r2b0,
    const float* __restrict__ r2W1, const float* __restrict__ r2b1,
    const float* __restrict__ r3W0, const float* __restrict__ r3b0,
    const float* __restrict__ r3W1, const float* __restrict__ r3b1,
    const float* __restrict__ eW0, const float* __restrict__ eb0p,
    const float* __restrict__ eW1, const float* __restrict__ eb1p,
    float* __restrict__ out) {
  const int lane = threadIdx.x & 63;
  const int eh = lane >> 5;         // element half 0/1
  const int g = (lane >> 3) & 3;    // 8-lane group within half
  const int i = lane & 7;           // neuron lane within group
  const int e0 = __builtin_amdgcn_readfirstlane(
      (blockIdx.x * 4 + (threadIdx.x >> 6)) * 2);
  const int e = e0 + eh;            // per-lane element

  // Weights per group: g0,g1 -> NN1 (r1); g2 -> NN3 (r3); g3 -> NN2 (r2).
  const float* W0p = (g == 3) ? r2W0 : (g == 2) ? r3W0 : r1W0;
  const float* b0p = (g == 3) ? r2b0 : (g == 2) ? r3b0 : r1b0;
  const float* W1p = (g == 3) ? r2W1 : (g == 2) ? r3W1 : r1W1;

  const v2f w0s = {W0p[i] * L2E2, W0p[i + 8] * L2E2};
  const v2f b0s = {b0p[i] * L2E2, b0p[i + 8] * L2E2};
  const v2f iwn = {1.0f / (-2.0f * W1p[i]),
                   1.0f / (-2.0f * W1p[i + 8])};  // init-only divides

  float C1 = r1b1[0], C2 = r2b1[0], C3 = r3b1[0];
  for (int q = 0; q < 16; ++q) {
    C1 += r1W1[q];
    C2 += r2W1[q];
    C3 += r3W1[q];
  }
  const float caC = 0.2f - C1;
  const float cbC = -1.0f / 6.0f + (5.0f / 3.0f) * C1 - 3.0f * C2 + C3;
  const float ccC = -1.0f / 6.0f + C2 - C3;

  // Per-lane state & combine constants.
  const int strow = (g <= 1) ? 0 : (g == 2) ? 2 : 1;  // A,A,C,B
  const float cstBase = (g == 3) ? cbC : (g == 2) ? ccC : caC;
  const float uco = (g <= 1) ? 0.1f : 0.0f;
  const float c_own = (g == 3) ? -3.0f : -1.0f;
  const float c_qr = (g >= 2) ? 1.0f : 0.0f;
  const float c_m2 = (g == 3) ? (5.0f / 3.0f) : 0.0f;

  float S = x0[e * 15 + strow];

  // estC weights: neuron n = lane & 31.
  const int n = lane & 31;
  const float eb0v = eb0p[n] * L2E2;
  const float ew0 = eW0[0 * 32 + n] * L2E2;
  const float ew1 = eW0[1 * 32 + n] * L2E2;
  const float ew2 = eW0[2 * 32 + n] * L2E2;
  const float ew3 = eW0[3 * 32 + n] * L2E2;
  const float ew4 = eW0[4 * 32 + n] * L2E2;
  const float ew5 = eW0[5 * 32 + n] * L2E2;
  const float ew6 = eW0[6 * 32 + n] * L2E2;
  const float ew7 = eW0[7 * 32 + n] * L2E2;
  const float ew8 = eW0[8 * 32 + n] * L2E2;
  const float ew9 = eW0[9 * 32 + n] * L2E2;
  const float ew10 = eW0[10 * 32 + n] * L2E2;
  const float ew11 = eW0[11 * 32 + n] * L2E2;
  const float ew1n = -2.0f * eW1[n];
  float ebs = eb1p[0];
  for (int q = 0; q < 32; ++q) ebs += eW1[q];
  const float eb32 = ebs * 0.03125f;  // output bias folded per-lane

  // z-history (per-lane regs, own element's): pairs (A,B) oldest..newest.
  const float* zp = x0 + e * 15 + 3;
  float hA0 = zp[0], hB0 = zp[1], hA1 = zp[2], hB1 = zp[3];
  float hA2 = zp[4], hB2 = zp[5], hA3 = zp[6], hB3 = zp[7];
  float hU0 = zp[8], hU1 = zp[9], hU2 = zp[10], hU3 = zp[11];

  const float* up0 = useq + e0 * TT;        // uniform -> s_load prefetch
  const float* up1 = useq + (e0 + 1) * TT;
  // Store lanes per half: 0 -> comp0 (A), 24 -> comp1 (B), 16 -> comp2 (C),
  // 17 -> comp3 (estC).
  const int l31 = lane & 31;
  const int soff = (l31 == 0) ? 0 : (l31 == 24) ? 1 : (l31 == 16) ? 2 : 3;
  float* op = out + (size_t)e * TT * 4 + soff;
  const bool sflag = (l31 == 0) | (l31 == 24) | (l31 == 16) | (l31 == 17);
  const bool isE = (l31 == 17);

#define STAGE(SS, KK)                                                     \
  {                                                                       \
    v2f h = __builtin_elementwise_fma(w0s, (v2f){(SS), (SS)}, b0s);       \
    h.x = __builtin_amdgcn_exp2f(h.x);                                    \
    h.y = __builtin_amdgcn_exp2f(h.y);                                    \
    h = __builtin_elementwise_fma(h, iwn, iwn);                           \
    float rv = __builtin_amdgcn_rcpf(h.x) + __builtin_amdgcn_rcpf(h.y);   \
    float q = sum8(rv);                                                   \
    float qr = dpp_mov<0x128>(q);   /* row_ror:8 */                       \
    float m2 = dpp_mov<0x142>(qr);  /* row_bcast15 */                     \
    float t_ = fmaf(-0.1f, (SS), cstS);                                   \
    t_ = fmaf(c_own, q, t_);                                              \
    t_ = fmaf(c_qr, qr, t_);                                              \
    KK = fmaf(c_m2, m2, t_);                                              \
  }

// One time-step for both elements. estC first (independent chain -> fills
// RK stalls); history passed/produced by name (zero-cost rotation).
#define STEP(UA, UB, SC_, hA0_, hB0_, hA1_, hB1_, hA2_, hB2_, hA3_, hB3_, \
             hU0_, hU1_, hU2_, hU3_, NA_, NB_, NU_)                       \
  {                                                                       \
    float a_ = fmaf((hA0_), ew0, eb0v);                                   \
    a_ = fmaf((hB0_), ew1, a_);                                           \
    a_ = fmaf((hA1_), ew2, a_);                                           \
    a_ = fmaf((hB1_), ew3, a_);                                           \
    a_ = fmaf((hA2_), ew4, a_);                                           \
    a_ = fmaf((hB2_), ew5, a_);                                           \
    a_ = fmaf((hA3_), ew6, a_);                                           \
    a_ = fmaf((hB3_), ew7, a_);                                           \
    a_ = fmaf((hU0_), ew8, a_);                                           \
    a_ = fmaf((hU1_), ew9, a_);                                           \
    a_ = fmaf((hU2_), ew10, a_);                                          \
    a_ = fmaf((hU3_), ew11, a_);                                          \
    float er_ = __builtin_amdgcn_rcpf(__builtin_amdgcn_exp2f(a_) + 1.0f); \
    float ps_ = fmaf(ew1n, er_, eb32);                                    \
    ps_ = dpp_add<0xB1>(ps_);                                             \
    ps_ = dpp_add<0x4E>(ps_);                                             \
    ps_ = dpp_add<0x141>(ps_);                                            \
    ps_ = dpp_add<0x140>(ps_);   /* per-16-row sums */                    \
    ps_ = dpp_add<0x142>(ps_);   /* rows 1,3: full 32-neuron sums */      \
    const float sAa_ = rdlane(S, 0);                                      \
    const float sBa_ = rdlane(S, 24);                                     \
    const float sAb_ = rdlane(S, 32);                                     \
    const float sBb_ = rdlane(S, 56);                                     \
    NA_ = eh ? sAb_ : sAa_;                                               \
    NB_ = eh ? sBb_ : sBa_;                                               \
    const float usel_ = eh ? (UB) : (UA);                                 \
    NU_ = usel_;                                                          \
    const float cstS = fmaf(uco, usel_, cstBase);                         \
    SC_ = isE ? ps_ : S;                                                  \
    float k1, k2, k3, k4;                                                 \
    STAGE(S, k1)                                                          \
    float s2 = fmaf(0.5f, k1, S);                                         \
    STAGE(s2, k2)                                                         \
    float s3 = fmaf(0.5f, k2, S);                                         \
    STAGE(s3, k3)                                                         \
    float s4 = S + k3;                                                    \
    STAGE(s4, k4)                                                         \
    S = fmaf(1.0f / 6.0f, fmaf(2.0f, k2 + k3, k1) + k4, S);               \
  }

  float4 cura = *(const float4*)(up0);
  float4 curb = *(const float4*)(up1);

  for (int t0 = 0; t0 < TT; t0 += 4) {
    const int tn = (t0 + 4 <= TT - 4) ? (t0 + 4) : (TT - 4);
    const float4 naa = *(const float4*)(up0 + tn);
    const float4 nab = *(const float4*)(up1 + tn);

    float sc0, sc1, sc2, sc3;
    float A4, B4, U4, A5, B5, U5, A6, B6, U6, A7, B7, U7;
    STEP(cura.x, curb.x, sc0, hA0, hB0, hA1, hB1, hA2, hB2, hA3, hB3,
         hU0, hU1, hU2, hU3, A4, B4, U4)
    STEP(cura.y, curb.y, sc1, hA1, hB1, hA2, hB2, hA3, hB3, A4, B4,
         hU1, hU2, hU3, U4, A5, B5, U5)
    STEP(cura.z, curb.z, sc2, hA2, hB2, hA3, hB3, A4, B4, A5, B5,
         hU2, hU3, U4, U5, A6, B6, U6)
    STEP(cura.w, curb.w, sc3, hA3, hB3, A4, B4, A5, B5, A6, B6,
         hU3, U4, U5, U6, A7, B7, U7)

    // Batched stores: lanes {0,24,16,17} (e0) and +32 (e1) write comps
    // {0,1,2,3} for 4 steps.
    if (sflag) {
      float* p = op + t0 * 4;
      p[0] = sc0;  p[4] = sc1;  p[8] = sc2;  p[12] = sc3;
    }

    hA0 = A4; hB0 = B4; hA1 = A5; hB1 = B5;
    hA2 = A6; hB2 = B6; hA3 = A7; hB3 = B7;
    hU0 = U4; hU1 = U5; hU2 = U6; hU3 = U7;

    cura = naa;
    curb = nab;
  }
#undef STEP
#undef STAGE
}

// ---------------------------------------------------------------------------
extern "C" void kernel_launch(void* const* d_in, const int* in_sizes, int n_in,
                              void* d_out, int out_size, void* d_ws,
                              size_t ws_size, hipStream_t stream) {
  const float* useq = (const float*)d_in[0];
  const float* x0 = (const float*)d_in[1];
  float* out = (float*)d_out;

  phase1_kernel<<<BB / 8, 256, 0, stream>>>(
      useq, x0,
      (const float*)d_in[2], (const float*)d_in[3], (const float*)d_in[4],
      (const float*)d_in[5], (const float*)d_in[6], (const float*)d_in[7],
      (const float*)d_in[8], (const float*)d_in[9], (const float*)d_in[10],
      (const float*)d_in[11], (const float*)d_in[12], (const float*)d_in[13],
      (const float*)d_in[14], (const float*)d_in[15], (const float*)d_in[16],
      (const float*)d_in[17], out);
}